// Round 8
// baseline (853.856 us; speedup 1.0000x reference)
//
#include <hip/hip_runtime.h>

#define D 64
#define NNODES 100000
#define NGRAPHS 128
#define NTILES ((NNODES + 15) / 16)   // 6250
#define BUCKW 512                     // nodes per bucket (power of 2)
#define NBUCK ((NNODES + BUCKW - 1) / BUCKW)   // 196

typedef unsigned int uint;
typedef unsigned short ushort;
typedef __attribute__((ext_vector_type(8))) short short8;   // 8 bf16 (4 VGPRs)
typedef __attribute__((ext_vector_type(4))) float f32x4;

// ---- bf16 helpers (RNE) ----
__device__ __forceinline__ ushort f2b(float f) {
    uint u = __float_as_uint(f);
    uint r = (u + 0x7fffu + ((u >> 16) & 1u)) >> 16;
    return (ushort)r;
}
__device__ __forceinline__ float b2f(ushort h) {
    return __uint_as_float(((uint)h) << 16);
}

// ---------------- zero buffer (int4 grid-stride) ----------------
__global__ void zero_kernel(int* __restrict__ buf, int n4) {
    int i = blockIdx.x * blockDim.x + threadIdx.x;
    int stride = gridDim.x * blockDim.x;
    int4 z = make_int4(0, 0, 0, 0);
    for (; i < n4; i += stride) ((int4*)buf)[i] = z;
}

// ---------------- f32 -> bf16 cast (float4 in, ushort4 out) ----------------
__global__ void cast_kernel(const float* __restrict__ in, ushort* __restrict__ outb, int n4) {
    int i = blockIdx.x * blockDim.x + threadIdx.x;
    int stride = gridDim.x * blockDim.x;
    for (; i < n4; i += stride) {
        float4 v = ((const float4*)in)[i];
        ushort4 o;
        o.x = f2b(v.x); o.y = f2b(v.y); o.z = f2b(v.z); o.w = f2b(v.w);
        ((ushort4*)outb)[i] = o;
    }
}

// -------- swizzle W1 (f32 [k][col] row-major) into MFMA B-fragment order --------
__global__ void prep_w_kernel(const float* __restrict__ W, ushort* __restrict__ Wswz) {
    int t = threadIdx.x;            // 0..511 = j*64 + lane
    int j = t >> 6, lane = t & 63;
    int c = j >> 1, h = j & 1;
    int col = 16 * c + (lane & 15);
    int kbase = (lane >> 4) * 8 + 32 * h;
#pragma unroll
    for (int i = 0; i < 8; ++i)
        Wswz[(size_t)t * 8 + i] = f2b(W[(kbase + i) * D + col]);
}

// ---------------- pass A: per-bucket edge histogram (LDS-aggregated) ----------------
__global__ void bucket_count_kernel(const int* __restrict__ dst, int* __restrict__ bcnt, int nE) {
    __shared__ int sh[256];
    int t = threadIdx.x;
    sh[t] = 0;
    __syncthreads();
    int base = (blockIdx.x * 256 + t) * 4;
    if (base + 4 <= nE) {
        int4 d = *(const int4*)(dst + base);
        atomicAdd(&sh[d.x >> 9], 1);
        atomicAdd(&sh[d.y >> 9], 1);
        atomicAdd(&sh[d.z >> 9], 1);
        atomicAdd(&sh[d.w >> 9], 1);
    } else {
        for (int e = base; e < nE; ++e) atomicAdd(&sh[dst[e] >> 9], 1);
    }
    __syncthreads();
    if (sh[t]) atomicAdd(&bcnt[t], sh[t]);
}

// ---------------- pass B: scan 196 bucket counts -> bases + cursors ----------------
__global__ void bscan_kernel(const int* __restrict__ bcnt, int* __restrict__ bbase,
                             int* __restrict__ bcursor, int* __restrict__ off, int nE) {
    __shared__ int sh[256];
    int t = threadIdx.x;
    sh[t] = (t < NBUCK) ? bcnt[t] : 0;
    __syncthreads();
    for (int d = 1; d < 256; d <<= 1) {
        int u = (t >= d) ? sh[t - d] : 0;
        __syncthreads();
        sh[t] += u;
        __syncthreads();
    }
    int excl = (t == 0) ? 0 : sh[t - 1];
    if (t <= NBUCK) bbase[t] = (t == NBUCK) ? nE : excl;
    if (t < NBUCK) bcursor[t] = excl;
    if (t == 0) off[NNODES] = nE;
}

// ---------------- pass C: scatter packed (src<<9 | dstlocal) into bucket streams ----------------
// Cursor positions advance sequentially in time -> write streams coalesce in L2.
__global__ void bucket_scatter_kernel(const int* __restrict__ src, const int* __restrict__ dst,
                                      int* __restrict__ bcursor, int* __restrict__ packed, int nE) {
    int base = (blockIdx.x * 256 + threadIdx.x) * 4;
    if (base + 4 <= nE) {
        int4 d = *(const int4*)(dst + base);
        int4 s = *(const int4*)(src + base);
        int p0 = atomicAdd(&bcursor[d.x >> 9], 1);
        int p1 = atomicAdd(&bcursor[d.y >> 9], 1);
        int p2 = atomicAdd(&bcursor[d.z >> 9], 1);
        int p3 = atomicAdd(&bcursor[d.w >> 9], 1);
        packed[p0] = (s.x << 9) | (d.x & 511);
        packed[p1] = (s.y << 9) | (d.y & 511);
        packed[p2] = (s.z << 9) | (d.z & 511);
        packed[p3] = (s.w << 9) | (d.w & 511);
    } else {
        for (int e = base; e < nE; ++e) {
            int p = atomicAdd(&bcursor[dst[e] >> 9], 1);
            packed[p] = (src[e] << 9) | (dst[e] & 511);
        }
    }
}

// ---------------- pass D: per-bucket CSR build (one block per bucket) ----------------
// LDS histogram over the bucket's 512 nodes, LDS scan, then place esrc into the
// bucket's contiguous range (writes confined to a ~24KB window -> 1 writeback/line).
__global__ void csr_build_kernel(const int* __restrict__ packed, const int* __restrict__ bbase,
                                 int* __restrict__ off, int* __restrict__ esrc) {
    __shared__ int lcnt[BUCKW];
    __shared__ int lcur[BUCKW];
    __shared__ int part[256];
    int t = threadIdx.x;
    int blk = blockIdx.x;
    int ebeg = bbase[blk], eend = bbase[blk + 1];
    lcnt[t] = 0; lcnt[t + 256] = 0;
    __syncthreads();
    for (int e = ebeg + t; e < eend; e += 256)
        atomicAdd(&lcnt[packed[e] & 511], 1);
    __syncthreads();
    int a = lcnt[2 * t], bv = lcnt[2 * t + 1];
    part[t] = a + bv;
    __syncthreads();
    for (int d = 1; d < 256; d <<= 1) {
        int u = (t >= d) ? part[t - d] : 0;
        __syncthreads();
        part[t] += u;
        __syncthreads();
    }
    int excl2 = (t == 0) ? 0 : part[t - 1];
    lcur[2 * t] = excl2;
    lcur[2 * t + 1] = excl2 + a;
    int node0 = blk * BUCKW + 2 * t;
    if (node0 < NNODES)     off[node0]     = ebeg + excl2;
    if (node0 + 1 < NNODES) off[node0 + 1] = ebeg + excl2 + a;
    __syncthreads();
    for (int e = ebeg + t; e < eend; e += 256) {
        int p = packed[e];
        int pos = ebeg + atomicAdd(&lcur[p & 511], 1);
        esrc[pos] = p >> 9;
    }
}

// ---- bf16 gather with 8/4-wide ILP: one cache line per edge row ----
__device__ __forceinline__ float gather_row_b(const ushort* __restrict__ x,
                                              const int* __restrict__ esrc,
                                              int beg, int end, int lane, float acc) {
    int i = beg;
    while (i + 8 <= end) {
        int s0 = esrc[i + 0], s1 = esrc[i + 1], s2 = esrc[i + 2], s3 = esrc[i + 3];
        int s4 = esrc[i + 4], s5 = esrc[i + 5], s6 = esrc[i + 6], s7 = esrc[i + 7];
        ushort v0 = x[(size_t)s0 * D + lane], v1 = x[(size_t)s1 * D + lane];
        ushort v2 = x[(size_t)s2 * D + lane], v3 = x[(size_t)s3 * D + lane];
        ushort v4 = x[(size_t)s4 * D + lane], v5 = x[(size_t)s5 * D + lane];
        ushort v6 = x[(size_t)s6 * D + lane], v7 = x[(size_t)s7 * D + lane];
        acc += ((b2f(v0) + b2f(v1)) + (b2f(v2) + b2f(v3))) +
               ((b2f(v4) + b2f(v5)) + (b2f(v6) + b2f(v7)));
        i += 8;
    }
    if (i + 4 <= end) {
        int s0 = esrc[i + 0], s1 = esrc[i + 1], s2 = esrc[i + 2], s3 = esrc[i + 3];
        ushort v0 = x[(size_t)s0 * D + lane], v1 = x[(size_t)s1 * D + lane];
        ushort v2 = x[(size_t)s2 * D + lane], v3 = x[(size_t)s3 * D + lane];
        acc += (b2f(v0) + b2f(v1)) + (b2f(v2) + b2f(v3));
        i += 4;
    }
    for (; i < end; ++i) acc += b2f(x[(size_t)esrc[i] * D + lane]);
    return acc;
}

// ---------------- pure gather (CSR): aggb[node] = x[node] + sum_src x[src] ----------------
__global__ void gather_kernel(const ushort* __restrict__ xb,
                              const int* __restrict__ off,
                              const int* __restrict__ esrc,
                              ushort* __restrict__ aggb, int n) {
    int tid = threadIdx.x;
    int w = tid >> 6, lane = tid & 63;
    int node = blockIdx.x * 4 + w;
    int stride = gridDim.x * 4;
    for (; node < n; node += stride) {
        float acc = b2f(xb[(size_t)node * D + lane]);
        acc = gather_row_b(xb, esrc, off[node], off[node + 1], lane, acc);
        aggb[(size_t)node * D + lane] = f2b(acc);
    }
}

// ---------------- MFMA GEMM: hb = bf16(relu(aggb @ W1 + b1)) ----------------
__global__ void gemm1_kernel(const ushort* __restrict__ aggb,
                             const ushort* __restrict__ Wswz,
                             const float* __restrict__ b1,
                             ushort* __restrict__ hb, int ntiles) {
    int tid = threadIdx.x;
    int w = tid >> 6, lane = tid & 63;
    int tile = blockIdx.x * 4 + w;
    if (tile >= ntiles) return;

    short8 bfrag[8];
#pragma unroll
    for (int j = 0; j < 8; ++j)
        bfrag[j] = *(const short8*)(Wswz + ((size_t)j * 64 + lane) * 8);

    int rbase = tile * 16;
    const ushort* arow = aggb + (size_t)(rbase + (lane & 15)) * D + (lane >> 4) * 8;
    short8 a0 = *(const short8*)(arow);
    short8 a1 = *(const short8*)(arow + 32);

    f32x4 acc0 = {0.f, 0.f, 0.f, 0.f};
    f32x4 acc1 = {0.f, 0.f, 0.f, 0.f};
    f32x4 acc2 = {0.f, 0.f, 0.f, 0.f};
    f32x4 acc3 = {0.f, 0.f, 0.f, 0.f};
    acc0 = __builtin_amdgcn_mfma_f32_16x16x32_bf16(a0, bfrag[0], acc0, 0, 0, 0);
    acc0 = __builtin_amdgcn_mfma_f32_16x16x32_bf16(a1, bfrag[1], acc0, 0, 0, 0);
    acc1 = __builtin_amdgcn_mfma_f32_16x16x32_bf16(a0, bfrag[2], acc1, 0, 0, 0);
    acc1 = __builtin_amdgcn_mfma_f32_16x16x32_bf16(a1, bfrag[3], acc1, 0, 0, 0);
    acc2 = __builtin_amdgcn_mfma_f32_16x16x32_bf16(a0, bfrag[4], acc2, 0, 0, 0);
    acc2 = __builtin_amdgcn_mfma_f32_16x16x32_bf16(a1, bfrag[5], acc2, 0, 0, 0);
    acc3 = __builtin_amdgcn_mfma_f32_16x16x32_bf16(a0, bfrag[6], acc3, 0, 0, 0);
    acc3 = __builtin_amdgcn_mfma_f32_16x16x32_bf16(a1, bfrag[7], acc3, 0, 0, 0);

    // C layout: col = 16c + (lane&15), row = (lane>>4)*4 + r
    int colb = lane & 15;
    int rowb = (lane >> 4) * 4;
#pragma unroll
    for (int r = 0; r < 4; ++r) {
        size_t rowoff = (size_t)(rbase + rowb + r) * D;
        hb[rowoff + colb +  0] = f2b(fmaxf(acc0[r] + b1[colb +  0], 0.f));
        hb[rowoff + colb + 16] = f2b(fmaxf(acc1[r] + b1[colb + 16], 0.f));
        hb[rowoff + colb + 32] = f2b(fmaxf(acc2[r] + b1[colb + 32], 0.f));
        hb[rowoff + colb + 48] = f2b(fmaxf(acc3[r] + b1[colb + 48], 0.f));
    }
}

// ------- gather2 (CSR) + pre-GEMM pooling: P[g] = sum_{node in g} (h[node]+agg2[node]) -------
__global__ void gather_pool_kernel(const ushort* __restrict__ hb,
                                   const int* __restrict__ off,
                                   const int* __restrict__ esrc,
                                   const int* __restrict__ gid,
                                   float* __restrict__ P,
                                   float* __restrict__ cntg, int n) {
    int tid = threadIdx.x;
    int w = tid >> 6, lane = tid & 63;
    int waves_total = gridDim.x * 4;
    int wave_id = blockIdx.x * 4 + w;
    int chunk = (n + waves_total - 1) / waves_total;
    int start = wave_id * chunk;
    int end = min(start + chunk, n);

    float accp = 0.f;
    int cur = -1, cc = 0;
    for (int node = start; node < end; ++node) {
        float acc = b2f(hb[(size_t)node * D + lane]);
        acc = gather_row_b(hb, esrc, off[node], off[node + 1], lane, acc);
        int g = gid[node];            // uniform across the wave (sorted)
        if (g != cur) {
            if (cur >= 0) {
                atomicAdd(&P[cur * D + lane], accp);
                if (lane == 0) atomicAdd(&cntg[cur], (float)cc);
            }
            cur = g; accp = 0.f; cc = 0;
        }
        accp += acc;
        cc++;
    }
    if (cur >= 0) {
        atomicAdd(&P[cur * D + lane], accp);
        if (lane == 0) atomicAdd(&cntg[cur], (float)cc);
    }
}

// ------- final tiny GEMM: out[g] = P[g] @ W2 + cntg[g] * b2 (f32) -------
__global__ void final_kernel(const float* __restrict__ P,
                             const float* __restrict__ cntg,
                             const float* __restrict__ W2,
                             const float* __restrict__ b2,
                             float* __restrict__ out) {
    __shared__ float Ws[D * D];
    __shared__ float bs[D];
    __shared__ float xs[4][D];
    int tid = threadIdx.x;
    for (int i = tid; i < D * D / 4; i += blockDim.x)
        ((float4*)Ws)[i] = ((const float4*)W2)[i];
    if (tid < D) bs[tid] = b2[tid];
    __syncthreads();

    int w = tid >> 6, lane = tid & 63;
    int g = blockIdx.x * 4 + w;
    if (g >= NGRAPHS) return;
    xs[w][lane] = P[g * D + lane];
    float acc = cntg[g] * bs[lane];
#pragma unroll
    for (int k = 0; k < D; ++k)
        acc = fmaf(xs[w][k], Ws[k * D + lane], acc);
    out[g * D + lane] = acc;
}

extern "C" void kernel_launch(void* const* d_in, const int* in_sizes, int n_in,
                              void* d_out, int out_size, void* d_ws, size_t ws_size,
                              hipStream_t stream) {
    const float* feats = (const float*)d_in[0];
    const int*   src   = (const int*)d_in[1];
    const int*   dst   = (const int*)d_in[2];
    const int*   gid   = (const int*)d_in[3];
    const float* W1    = (const float*)d_in[4];
    const float* b1    = (const float*)d_in[5];
    const float* W2    = (const float*)d_in[6];
    const float* b2    = (const float*)d_in[7];
    float* out = (float*)d_out;

    int nE = in_sizes[1];

    // workspace layout (all segments 16B-aligned)
    int*    bcnt   = (int*)d_ws;                        // 256 ints
    int*    bbase  = bcnt + 256;                        // 256 ints (NBUCK+1 used)
    int*    bcursor= bbase + 256;                       // 256 ints
    float*  P      = (float*)(bcursor + 256);           // 128*64 f32
    float*  cntg   = P + NGRAPHS * D;                   // 128 f32
    int*    off    = (int*)(cntg + 128);                // NNODES+4 ints
    int*    packed = off + ((NNODES + 7) & ~3);         // nE ints
    int*    esrc   = packed + ((nE + 3) & ~3);          // nE ints
    ushort* Wswz   = (ushort*)(esrc + ((nE + 3) & ~3)); // 4096 bf16
    ushort* xb     = Wswz + 4096;                       // NNODES*D bf16
    ushort* aggb   = xb + (size_t)NNODES * D;           // NNODES*D bf16
    ushort* hb     = aggb + (size_t)NNODES * D;         // NNODES*D bf16

    int e4Blocks = (nE / 4 + 255) / 256 + 1;

    // ---- CSR build via 2-level bucket counting sort (coalescing write streams) ----
    zero_kernel<<<1, 256, 0, stream>>>(bcnt, 256 / 4);
    bucket_count_kernel<<<e4Blocks, 256, 0, stream>>>(dst, bcnt, nE);
    bscan_kernel<<<1, 256, 0, stream>>>(bcnt, bbase, bcursor, off, nE);
    bucket_scatter_kernel<<<e4Blocks, 256, 0, stream>>>(src, dst, bcursor, packed, nE);
    csr_build_kernel<<<NBUCK, 256, 0, stream>>>(packed, bbase, off, esrc);

    // ---- prep: cast feats to bf16, swizzle W1, zero P/cntg ----
    cast_kernel<<<2048, 256, 0, stream>>>(feats, xb, NNODES * D / 4);
    prep_w_kernel<<<1, 512, 0, stream>>>(W1, Wswz);
    zero_kernel<<<8, 256, 0, stream>>>((int*)P, (NGRAPHS * D + 128) / 4);

    // ---- layer 1: gather then MFMA GEMM ----
    gather_kernel<<<2048, 256, 0, stream>>>(xb, off, esrc, aggb, NNODES);
    gemm1_kernel<<<(NTILES + 3) / 4, 256, 0, stream>>>(aggb, Wswz, b1, hb, NTILES);

    // ---- layer 2: gather + pooled pre-GEMM sum, then tiny final GEMM ----
    gather_pool_kernel<<<2048, 256, 0, stream>>>(hb, off, esrc, gid, P, cntg, NNODES);
    final_kernel<<<NGRAPHS / 4, 256, 0, stream>>>(P, cntg, W2, b2, out);
}

// Round 9
// 253.518 us; speedup vs baseline: 3.3680x; 3.3680x over previous
//
#include <hip/hip_runtime.h>

#define D 64
#define NNODES 100000
#define NGRAPHS 128
#define NTILES ((NNODES + 15) / 16)   // 6250
#define BUCKW 512                     // nodes per bucket (power of 2)
#define NBUCK ((NNODES + BUCKW - 1) / BUCKW)   // 196
#define EPB 4096                      // edges per binning block (16/thread)

typedef unsigned int uint;
typedef unsigned short ushort;
typedef __attribute__((ext_vector_type(8))) short short8;   // 8 bf16 (4 VGPRs)
typedef __attribute__((ext_vector_type(4))) float f32x4;

// ---- bf16 helpers (RNE) ----
__device__ __forceinline__ ushort f2b(float f) {
    uint u = __float_as_uint(f);
    uint r = (u + 0x7fffu + ((u >> 16) & 1u)) >> 16;
    return (ushort)r;
}
__device__ __forceinline__ float b2f(ushort h) {
    return __uint_as_float(((uint)h) << 16);
}

// ---------------- zero buffer (int4 grid-stride) ----------------
__global__ void zero_kernel(int* __restrict__ buf, int n4) {
    int i = blockIdx.x * blockDim.x + threadIdx.x;
    int stride = gridDim.x * blockDim.x;
    int4 z = make_int4(0, 0, 0, 0);
    for (; i < n4; i += stride) ((int4*)buf)[i] = z;
}

// ---------------- f32 -> bf16 cast (float4 in, ushort4 out) ----------------
__global__ void cast_kernel(const float* __restrict__ in, ushort* __restrict__ outb, int n4) {
    int i = blockIdx.x * blockDim.x + threadIdx.x;
    int stride = gridDim.x * blockDim.x;
    for (; i < n4; i += stride) {
        float4 v = ((const float4*)in)[i];
        ushort4 o;
        o.x = f2b(v.x); o.y = f2b(v.y); o.z = f2b(v.z); o.w = f2b(v.w);
        ((ushort4*)outb)[i] = o;
    }
}

// -------- swizzle W1 (f32 [k][col] row-major) into MFMA B-fragment order --------
__global__ void prep_w_kernel(const float* __restrict__ W, ushort* __restrict__ Wswz) {
    int t = threadIdx.x;            // 0..511 = j*64 + lane
    int j = t >> 6, lane = t & 63;
    int c = j >> 1, h = j & 1;
    int col = 16 * c + (lane & 15);
    int kbase = (lane >> 4) * 8 + 32 * h;
#pragma unroll
    for (int i = 0; i < 8; ++i)
        Wswz[(size_t)t * 8 + i] = f2b(W[(kbase + i) * D + col]);
}

// ---- pass 1: per-block bucket histogram (LDS), written bucket-major, NO global atomics ----
__global__ void bhist_kernel(const int* __restrict__ dst, int* __restrict__ ghist,
                             int nE, int nblk) {
    __shared__ int lh[NBUCK];
    int t = threadIdx.x, blk = blockIdx.x;
    for (int i = t; i < NBUCK; i += 256) lh[i] = 0;
    __syncthreads();
    int base = blk * EPB + t * 16;
    if (base + 16 <= nE) {
#pragma unroll
        for (int j = 0; j < 4; ++j) {
            int4 d = *(const int4*)(dst + base + j * 4);
            atomicAdd(&lh[d.x >> 9], 1);
            atomicAdd(&lh[d.y >> 9], 1);
            atomicAdd(&lh[d.z >> 9], 1);
            atomicAdd(&lh[d.w >> 9], 1);
        }
    } else {
        int lim = min(base + 16, nE);
        for (int e = base; e < lim; ++e) atomicAdd(&lh[dst[e] >> 9], 1);
    }
    __syncthreads();
    for (int i = t; i < NBUCK; i += 256) ghist[(size_t)i * nblk + blk] = lh[i];
}

// ---- pass 2: exclusive scan (bucket-major) over ghist -> per-(bucket,block) bases ----
__global__ void gscan_kernel(int* __restrict__ g, int* __restrict__ bbase,
                             int M, int nblk, int nE) {
    __shared__ int part[1024];
    int t = threadIdx.x;
    int C = (M + 1023) >> 10;
    int beg = t * C, end = min(beg + C, M);
    int s = 0;
    for (int i = beg; i < end; ++i) s += g[i];
    part[t] = s;
    __syncthreads();
    for (int d = 1; d < 1024; d <<= 1) {
        int u = (t >= d) ? part[t - d] : 0;
        __syncthreads();
        part[t] += u;
        __syncthreads();
    }
    int run = (t == 0) ? 0 : part[t - 1];
    for (int i = beg; i < end; ++i) {
        int v = g[i];
        g[i] = run;                       // exclusive base for (bucket, block)
        if (i % nblk == 0) bbase[i / nblk] = run;   // bucket start
        run += v;
    }
    if (t == 0) bbase[NBUCK] = nE;
}

// ---- pass 3: scatter packed (src<<9 | dstlocal); LDS cursors, sequential stream writes ----
__global__ void bscatter_kernel(const int* __restrict__ src, const int* __restrict__ dst,
                                const int* __restrict__ gbase, int* __restrict__ packed,
                                int nE, int nblk) {
    __shared__ int lcur[NBUCK];
    int t = threadIdx.x, blk = blockIdx.x;
    for (int i = t; i < NBUCK; i += 256) lcur[i] = gbase[(size_t)i * nblk + blk];
    __syncthreads();
    int base = blk * EPB + t * 16;
    if (base + 16 <= nE) {
#pragma unroll
        for (int j = 0; j < 4; ++j) {
            int4 d = *(const int4*)(dst + base + j * 4);
            int4 s4 = *(const int4*)(src + base + j * 4);
            int p0 = atomicAdd(&lcur[d.x >> 9], 1);
            int p1 = atomicAdd(&lcur[d.y >> 9], 1);
            int p2 = atomicAdd(&lcur[d.z >> 9], 1);
            int p3 = atomicAdd(&lcur[d.w >> 9], 1);
            packed[p0] = (s4.x << 9) | (d.x & 511);
            packed[p1] = (s4.y << 9) | (d.y & 511);
            packed[p2] = (s4.z << 9) | (d.z & 511);
            packed[p3] = (s4.w << 9) | (d.w & 511);
        }
    } else {
        int lim = min(base + 16, nE);
        for (int e = base; e < lim; ++e) {
            int p = atomicAdd(&lcur[dst[e] >> 9], 1);
            packed[p] = (src[e] << 9) | (dst[e] & 511);
        }
    }
}

// ---------------- pass 4: per-bucket CSR build (one block per bucket) ----------------
__global__ void csr_build_kernel(const int* __restrict__ packed, const int* __restrict__ bbase,
                                 int* __restrict__ off, int* __restrict__ esrc) {
    __shared__ int lcnt[BUCKW];
    __shared__ int lcur[BUCKW];
    __shared__ int part[256];
    int t = threadIdx.x;
    int blk = blockIdx.x;
    int ebeg = bbase[blk], eend = bbase[blk + 1];
    lcnt[t] = 0; lcnt[t + 256] = 0;
    __syncthreads();
    for (int e = ebeg + t; e < eend; e += 256)
        atomicAdd(&lcnt[packed[e] & 511], 1);
    __syncthreads();
    int a = lcnt[2 * t], bv = lcnt[2 * t + 1];
    part[t] = a + bv;
    __syncthreads();
    for (int d = 1; d < 256; d <<= 1) {
        int u = (t >= d) ? part[t - d] : 0;
        __syncthreads();
        part[t] += u;
        __syncthreads();
    }
    int excl2 = (t == 0) ? 0 : part[t - 1];
    lcur[2 * t] = excl2;
    lcur[2 * t + 1] = excl2 + a;
    int node0 = blk * BUCKW + 2 * t;
    if (node0 < NNODES)     off[node0]     = ebeg + excl2;
    if (node0 + 1 < NNODES) off[node0 + 1] = ebeg + excl2 + a;
    __syncthreads();
    for (int e = ebeg + t; e < eend; e += 256) {
        int p = packed[e];
        int pos = ebeg + atomicAdd(&lcur[p & 511], 1);
        esrc[pos] = p >> 9;
    }
}

// ---- bf16 gather with 8/4-wide ILP: one cache line per edge row ----
__device__ __forceinline__ float gather_row_b(const ushort* __restrict__ x,
                                              const int* __restrict__ esrc,
                                              int beg, int end, int lane, float acc) {
    int i = beg;
    while (i + 8 <= end) {
        int s0 = esrc[i + 0], s1 = esrc[i + 1], s2 = esrc[i + 2], s3 = esrc[i + 3];
        int s4 = esrc[i + 4], s5 = esrc[i + 5], s6 = esrc[i + 6], s7 = esrc[i + 7];
        ushort v0 = x[(size_t)s0 * D + lane], v1 = x[(size_t)s1 * D + lane];
        ushort v2 = x[(size_t)s2 * D + lane], v3 = x[(size_t)s3 * D + lane];
        ushort v4 = x[(size_t)s4 * D + lane], v5 = x[(size_t)s5 * D + lane];
        ushort v6 = x[(size_t)s6 * D + lane], v7 = x[(size_t)s7 * D + lane];
        acc += ((b2f(v0) + b2f(v1)) + (b2f(v2) + b2f(v3))) +
               ((b2f(v4) + b2f(v5)) + (b2f(v6) + b2f(v7)));
        i += 8;
    }
    if (i + 4 <= end) {
        int s0 = esrc[i + 0], s1 = esrc[i + 1], s2 = esrc[i + 2], s3 = esrc[i + 3];
        ushort v0 = x[(size_t)s0 * D + lane], v1 = x[(size_t)s1 * D + lane];
        ushort v2 = x[(size_t)s2 * D + lane], v3 = x[(size_t)s3 * D + lane];
        acc += (b2f(v0) + b2f(v1)) + (b2f(v2) + b2f(v3));
        i += 4;
    }
    for (; i < end; ++i) acc += b2f(x[(size_t)esrc[i] * D + lane]);
    return acc;
}

// ---------------- pure gather (CSR): aggb[node] = x[node] + sum_src x[src] ----------------
__global__ void gather_kernel(const ushort* __restrict__ xb,
                              const int* __restrict__ off,
                              const int* __restrict__ esrc,
                              ushort* __restrict__ aggb, int n) {
    int tid = threadIdx.x;
    int w = tid >> 6, lane = tid & 63;
    int node = blockIdx.x * 4 + w;
    int stride = gridDim.x * 4;
    for (; node < n; node += stride) {
        float acc = b2f(xb[(size_t)node * D + lane]);
        acc = gather_row_b(xb, esrc, off[node], off[node + 1], lane, acc);
        aggb[(size_t)node * D + lane] = f2b(acc);
    }
}

// ---------------- MFMA GEMM: hb = bf16(relu(aggb @ W1 + b1)) ----------------
__global__ void gemm1_kernel(const ushort* __restrict__ aggb,
                             const ushort* __restrict__ Wswz,
                             const float* __restrict__ b1,
                             ushort* __restrict__ hb, int ntiles) {
    int tid = threadIdx.x;
    int w = tid >> 6, lane = tid & 63;
    int tile = blockIdx.x * 4 + w;
    if (tile >= ntiles) return;

    short8 bfrag[8];
#pragma unroll
    for (int j = 0; j < 8; ++j)
        bfrag[j] = *(const short8*)(Wswz + ((size_t)j * 64 + lane) * 8);

    int rbase = tile * 16;
    const ushort* arow = aggb + (size_t)(rbase + (lane & 15)) * D + (lane >> 4) * 8;
    short8 a0 = *(const short8*)(arow);
    short8 a1 = *(const short8*)(arow + 32);

    f32x4 acc0 = {0.f, 0.f, 0.f, 0.f};
    f32x4 acc1 = {0.f, 0.f, 0.f, 0.f};
    f32x4 acc2 = {0.f, 0.f, 0.f, 0.f};
    f32x4 acc3 = {0.f, 0.f, 0.f, 0.f};
    acc0 = __builtin_amdgcn_mfma_f32_16x16x32_bf16(a0, bfrag[0], acc0, 0, 0, 0);
    acc0 = __builtin_amdgcn_mfma_f32_16x16x32_bf16(a1, bfrag[1], acc0, 0, 0, 0);
    acc1 = __builtin_amdgcn_mfma_f32_16x16x32_bf16(a0, bfrag[2], acc1, 0, 0, 0);
    acc1 = __builtin_amdgcn_mfma_f32_16x16x32_bf16(a1, bfrag[3], acc1, 0, 0, 0);
    acc2 = __builtin_amdgcn_mfma_f32_16x16x32_bf16(a0, bfrag[4], acc2, 0, 0, 0);
    acc2 = __builtin_amdgcn_mfma_f32_16x16x32_bf16(a1, bfrag[5], acc2, 0, 0, 0);
    acc3 = __builtin_amdgcn_mfma_f32_16x16x32_bf16(a0, bfrag[6], acc3, 0, 0, 0);
    acc3 = __builtin_amdgcn_mfma_f32_16x16x32_bf16(a1, bfrag[7], acc3, 0, 0, 0);

    // C layout: col = 16c + (lane&15), row = (lane>>4)*4 + r
    int colb = lane & 15;
    int rowb = (lane >> 4) * 4;
#pragma unroll
    for (int r = 0; r < 4; ++r) {
        size_t rowoff = (size_t)(rbase + rowb + r) * D;
        hb[rowoff + colb +  0] = f2b(fmaxf(acc0[r] + b1[colb +  0], 0.f));
        hb[rowoff + colb + 16] = f2b(fmaxf(acc1[r] + b1[colb + 16], 0.f));
        hb[rowoff + colb + 32] = f2b(fmaxf(acc2[r] + b1[colb + 32], 0.f));
        hb[rowoff + colb + 48] = f2b(fmaxf(acc3[r] + b1[colb + 48], 0.f));
    }
}

// ------- gather2 (CSR) + pre-GEMM pooling: P[g] = sum_{node in g} (h[node]+agg2[node]) -------
__global__ void gather_pool_kernel(const ushort* __restrict__ hb,
                                   const int* __restrict__ off,
                                   const int* __restrict__ esrc,
                                   const int* __restrict__ gid,
                                   float* __restrict__ P,
                                   float* __restrict__ cntg, int n) {
    int tid = threadIdx.x;
    int w = tid >> 6, lane = tid & 63;
    int waves_total = gridDim.x * 4;
    int wave_id = blockIdx.x * 4 + w;
    int chunk = (n + waves_total - 1) / waves_total;
    int start = wave_id * chunk;
    int end = min(start + chunk, n);

    float accp = 0.f;
    int cur = -1, cc = 0;
    for (int node = start; node < end; ++node) {
        float acc = b2f(hb[(size_t)node * D + lane]);
        acc = gather_row_b(hb, esrc, off[node], off[node + 1], lane, acc);
        int g = gid[node];            // uniform across the wave (sorted)
        if (g != cur) {
            if (cur >= 0) {
                atomicAdd(&P[cur * D + lane], accp);
                if (lane == 0) atomicAdd(&cntg[cur], (float)cc);
            }
            cur = g; accp = 0.f; cc = 0;
        }
        accp += acc;
        cc++;
    }
    if (cur >= 0) {
        atomicAdd(&P[cur * D + lane], accp);
        if (lane == 0) atomicAdd(&cntg[cur], (float)cc);
    }
}

// ------- final tiny GEMM: out[g] = P[g] @ W2 + cntg[g] * b2 (f32) -------
__global__ void final_kernel(const float* __restrict__ P,
                             const float* __restrict__ cntg,
                             const float* __restrict__ W2,
                             const float* __restrict__ b2,
                             float* __restrict__ out) {
    __shared__ float Ws[D * D];
    __shared__ float bs[D];
    __shared__ float xs[4][D];
    int tid = threadIdx.x;
    for (int i = tid; i < D * D / 4; i += blockDim.x)
        ((float4*)Ws)[i] = ((const float4*)W2)[i];
    if (tid < D) bs[tid] = b2[tid];
    __syncthreads();

    int w = tid >> 6, lane = tid & 63;
    int g = blockIdx.x * 4 + w;
    if (g >= NGRAPHS) return;
    xs[w][lane] = P[g * D + lane];
    float acc = cntg[g] * bs[lane];
#pragma unroll
    for (int k = 0; k < D; ++k)
        acc = fmaf(xs[w][k], Ws[k * D + lane], acc);
    out[g * D + lane] = acc;
}

extern "C" void kernel_launch(void* const* d_in, const int* in_sizes, int n_in,
                              void* d_out, int out_size, void* d_ws, size_t ws_size,
                              hipStream_t stream) {
    const float* feats = (const float*)d_in[0];
    const int*   src   = (const int*)d_in[1];
    const int*   dst   = (const int*)d_in[2];
    const int*   gid   = (const int*)d_in[3];
    const float* W1    = (const float*)d_in[4];
    const float* b1    = (const float*)d_in[5];
    const float* W2    = (const float*)d_in[6];
    const float* b2    = (const float*)d_in[7];
    float* out = (float*)d_out;

    int nE = in_sizes[1];
    int nblk = (nE + EPB - 1) / EPB;       // binning blocks (~293)
    int M = NBUCK * nblk;

    // workspace layout (all segments 16B-aligned)
    int*    bbase  = (int*)d_ws;                        // 256 ints (NBUCK+1 used)
    float*  P      = (float*)(bbase + 256);             // 128*64 f32
    float*  cntg   = P + NGRAPHS * D;                   // 128 f32
    int*    off    = (int*)(cntg + 128);                // NNODES+4 ints
    int*    ghist  = off + ((NNODES + 7) & ~3);         // M ints (~230KB)
    int*    packed = ghist + ((M + 3) & ~3);            // nE ints
    int*    esrc   = packed + ((nE + 3) & ~3);          // nE ints
    ushort* Wswz   = (ushort*)(esrc + ((nE + 3) & ~3)); // 4096 bf16
    ushort* xb     = Wswz + 4096;                       // NNODES*D bf16
    ushort* aggb   = xb + (size_t)NNODES * D;           // NNODES*D bf16
    ushort* hb     = aggb + (size_t)NNODES * D;         // NNODES*D bf16

    // ---- CSR build via atomic-free 3-pass binning + per-bucket build ----
    bhist_kernel<<<nblk, 256, 0, stream>>>(dst, ghist, nE, nblk);
    gscan_kernel<<<1, 1024, 0, stream>>>(ghist, bbase, M, nblk, nE);
    bscatter_kernel<<<nblk, 256, 0, stream>>>(src, dst, ghist, packed, nE, nblk);
    csr_build_kernel<<<NBUCK, 256, 0, stream>>>(packed, bbase, off, esrc);

    // ---- prep: cast feats to bf16, swizzle W1, zero P/cntg ----
    cast_kernel<<<2048, 256, 0, stream>>>(feats, xb, NNODES * D / 4);
    prep_w_kernel<<<1, 512, 0, stream>>>(W1, Wswz);
    zero_kernel<<<8, 256, 0, stream>>>((int*)P, (NGRAPHS * D + 128) / 4);

    // ---- layer 1: gather then MFMA GEMM ----
    gather_kernel<<<2048, 256, 0, stream>>>(xb, off, esrc, aggb, NNODES);
    gemm1_kernel<<<(NTILES + 3) / 4, 256, 0, stream>>>(aggb, Wswz, b1, hb, NTILES);

    // ---- layer 2: gather + pooled pre-GEMM sum, then tiny final GEMM ----
    gather_pool_kernel<<<2048, 256, 0, stream>>>(hb, off, esrc, gid, P, cntg, NNODES);
    final_kernel<<<NGRAPHS / 4, 256, 0, stream>>>(P, cntg, W2, b2, out);
}

// Round 10
// 173.709 us; speedup vs baseline: 4.9154x; 1.4594x over previous
//
#include <hip/hip_runtime.h>

#define D 64
#define NNODES 100000
#define NGRAPHS 128
#define NTILES ((NNODES + 15) / 16)   // 6250
#define BUCKW 512                     // nodes per bucket (power of 2)
#define NBUCK ((NNODES + BUCKW - 1) / BUCKW)   // 196
#define EPB 4096                      // edges per binning block (16/thread)

typedef unsigned int uint;
typedef unsigned short ushort;
typedef __attribute__((ext_vector_type(8))) short short8;   // 8 bf16 (4 VGPRs)
typedef __attribute__((ext_vector_type(4))) float f32x4;

// ---- bf16 helpers (RNE) ----
__device__ __forceinline__ ushort f2b(float f) {
    uint u = __float_as_uint(f);
    uint r = (u + 0x7fffu + ((u >> 16) & 1u)) >> 16;
    return (ushort)r;
}
__device__ __forceinline__ float b2f(ushort h) {
    return __uint_as_float(((uint)h) << 16);
}

// ---------------- zero buffer (int4 grid-stride) ----------------
__global__ void zero_kernel(int* __restrict__ buf, int n4) {
    int i = blockIdx.x * blockDim.x + threadIdx.x;
    int stride = gridDim.x * blockDim.x;
    int4 z = make_int4(0, 0, 0, 0);
    for (; i < n4; i += stride) ((int4*)buf)[i] = z;
}

// ---------------- f32 -> bf16 cast (float4 in, ushort4 out) ----------------
__global__ void cast_kernel(const float* __restrict__ in, ushort* __restrict__ outb, int n4) {
    int i = blockIdx.x * blockDim.x + threadIdx.x;
    int stride = gridDim.x * blockDim.x;
    for (; i < n4; i += stride) {
        float4 v = ((const float4*)in)[i];
        ushort4 o;
        o.x = f2b(v.x); o.y = f2b(v.y); o.z = f2b(v.z); o.w = f2b(v.w);
        ((ushort4*)outb)[i] = o;
    }
}

// -------- swizzle W1 (f32 [k][col] row-major) into MFMA B-fragment order --------
__global__ void prep_w_kernel(const float* __restrict__ W, ushort* __restrict__ Wswz) {
    int t = threadIdx.x;            // 0..511 = j*64 + lane
    int j = t >> 6, lane = t & 63;
    int c = j >> 1, h = j & 1;
    int col = 16 * c + (lane & 15);
    int kbase = (lane >> 4) * 8 + 32 * h;
#pragma unroll
    for (int i = 0; i < 8; ++i)
        Wswz[(size_t)t * 8 + i] = f2b(W[(kbase + i) * D + col]);
}

// ---- pass 1: per-block bucket histogram (LDS), written bucket-major, NO global atomics ----
__global__ void bhist_kernel(const int* __restrict__ dst, int* __restrict__ ghist,
                             int nE, int nblk) {
    __shared__ int lh[NBUCK];
    int t = threadIdx.x, blk = blockIdx.x;
    for (int i = t; i < NBUCK; i += 256) lh[i] = 0;
    __syncthreads();
    int base = blk * EPB + t * 16;
    if (base + 16 <= nE) {
#pragma unroll
        for (int j = 0; j < 4; ++j) {
            int4 d = *(const int4*)(dst + base + j * 4);
            atomicAdd(&lh[d.x >> 9], 1);
            atomicAdd(&lh[d.y >> 9], 1);
            atomicAdd(&lh[d.z >> 9], 1);
            atomicAdd(&lh[d.w >> 9], 1);
        }
    } else {
        int lim = min(base + 16, nE);
        for (int e = base; e < lim; ++e) atomicAdd(&lh[dst[e] >> 9], 1);
    }
    __syncthreads();
    for (int i = t; i < NBUCK; i += 256) ghist[(size_t)i * nblk + blk] = lh[i];
}

// ---- pass 2a: per-block coalesced reduction of ghist (1024 entries/block) ----
__global__ void gpartial_kernel(const int* __restrict__ g, int* __restrict__ gsum, int M) {
    __shared__ int sh[256];
    int t = threadIdx.x;
    int base = (blockIdx.x * 256 + t) * 4;
    int s = 0;
    if (base + 4 <= M) {
        int4 v = *(const int4*)(g + base);
        s = v.x + v.y + v.z + v.w;
    } else {
        for (int i = base; i < M; ++i) s += g[i];
    }
    sh[t] = s;
    __syncthreads();
    for (int d = 128; d > 0; d >>= 1) {
        if (t < d) sh[t] += sh[t + d];
        __syncthreads();
    }
    if (t == 0) gsum[blockIdx.x] = sh[0];
}

// ---- pass 2b: one small block scans the <=256 partial sums (exclusive) ----
__global__ void gscanb_kernel(const int* __restrict__ gsum, int* __restrict__ gbase2,
                              int* __restrict__ bbase, int* __restrict__ off,
                              int nb, int nE) {
    __shared__ int sh[256];
    int t = threadIdx.x;
    sh[t] = (t < nb) ? gsum[t] : 0;
    __syncthreads();
    for (int d = 1; d < 256; d <<= 1) {
        int u = (t >= d) ? sh[t - d] : 0;
        __syncthreads();
        sh[t] += u;
        __syncthreads();
    }
    if (t < nb) gbase2[t] = (t == 0) ? 0 : sh[t - 1];
    if (t == 0) {
        bbase[NBUCK] = nE;
        off[NNODES] = nE;
    }
}

// ---- pass 2c: per-block local scan + base -> exclusive bases in ghist; extract bbase ----
__global__ void goffsets_kernel(int* __restrict__ g, const int* __restrict__ gbase2,
                                int* __restrict__ bbase, int M, int nblk) {
    __shared__ int sh[256];
    int t = threadIdx.x;
    int base = (blockIdx.x * 256 + t) * 4;
    int v0 = 0, v1 = 0, v2 = 0, v3 = 0;
    if (base + 4 <= M) {
        int4 v = *(const int4*)(g + base);
        v0 = v.x; v1 = v.y; v2 = v.z; v3 = v.w;
    } else {
        if (base < M)     v0 = g[base];
        if (base + 1 < M) v1 = g[base + 1];
        if (base + 2 < M) v2 = g[base + 2];
        if (base + 3 < M) v3 = g[base + 3];
    }
    int s = v0 + v1 + v2 + v3;
    sh[t] = s;
    __syncthreads();
    for (int d = 1; d < 256; d <<= 1) {
        int u = (t >= d) ? sh[t - d] : 0;
        __syncthreads();
        sh[t] += u;
        __syncthreads();
    }
    int e0 = gbase2[blockIdx.x] + sh[t] - s;
    int e1 = e0 + v0, e2 = e1 + v1, e3 = e2 + v2;
    if (base + 4 <= M) {
        *(int4*)(g + base) = make_int4(e0, e1, e2, e3);
    } else {
        if (base < M)     g[base]     = e0;
        if (base + 1 < M) g[base + 1] = e1;
        if (base + 2 < M) g[base + 2] = e2;
        if (base + 3 < M) g[base + 3] = e3;
    }
    int ev[4] = {e0, e1, e2, e3};
#pragma unroll
    for (int j = 0; j < 4; ++j) {
        int i = base + j;
        if (i < M && i % nblk == 0) bbase[i / nblk] = ev[j];
    }
}

// ---- pass 3: scatter packed (src<<9 | dstlocal); LDS cursors, sequential stream writes ----
__global__ void bscatter_kernel(const int* __restrict__ src, const int* __restrict__ dst,
                                const int* __restrict__ gbase, int* __restrict__ packed,
                                int nE, int nblk) {
    __shared__ int lcur[NBUCK];
    int t = threadIdx.x, blk = blockIdx.x;
    for (int i = t; i < NBUCK; i += 256) lcur[i] = gbase[(size_t)i * nblk + blk];
    __syncthreads();
    int base = blk * EPB + t * 16;
    if (base + 16 <= nE) {
#pragma unroll
        for (int j = 0; j < 4; ++j) {
            int4 d = *(const int4*)(dst + base + j * 4);
            int4 s4 = *(const int4*)(src + base + j * 4);
            int p0 = atomicAdd(&lcur[d.x >> 9], 1);
            int p1 = atomicAdd(&lcur[d.y >> 9], 1);
            int p2 = atomicAdd(&lcur[d.z >> 9], 1);
            int p3 = atomicAdd(&lcur[d.w >> 9], 1);
            packed[p0] = (s4.x << 9) | (d.x & 511);
            packed[p1] = (s4.y << 9) | (d.y & 511);
            packed[p2] = (s4.z << 9) | (d.z & 511);
            packed[p3] = (s4.w << 9) | (d.w & 511);
        }
    } else {
        int lim = min(base + 16, nE);
        for (int e = base; e < lim; ++e) {
            int p = atomicAdd(&lcur[dst[e] >> 9], 1);
            packed[p] = (src[e] << 9) | (dst[e] & 511);
        }
    }
}

// ---------------- pass 4: per-bucket CSR build (one block per bucket) ----------------
__global__ void csr_build_kernel(const int* __restrict__ packed, const int* __restrict__ bbase,
                                 int* __restrict__ off, int* __restrict__ esrc) {
    __shared__ int lcnt[BUCKW];
    __shared__ int lcur[BUCKW];
    __shared__ int part[256];
    int t = threadIdx.x;
    int blk = blockIdx.x;
    int ebeg = bbase[blk], eend = bbase[blk + 1];
    lcnt[t] = 0; lcnt[t + 256] = 0;
    __syncthreads();
    for (int e = ebeg + t; e < eend; e += 256)
        atomicAdd(&lcnt[packed[e] & 511], 1);
    __syncthreads();
    int a = lcnt[2 * t], bv = lcnt[2 * t + 1];
    part[t] = a + bv;
    __syncthreads();
    for (int d = 1; d < 256; d <<= 1) {
        int u = (t >= d) ? part[t - d] : 0;
        __syncthreads();
        part[t] += u;
        __syncthreads();
    }
    int excl2 = (t == 0) ? 0 : part[t - 1];
    lcur[2 * t] = excl2;
    lcur[2 * t + 1] = excl2 + a;
    int node0 = blk * BUCKW + 2 * t;
    if (node0 < NNODES)     off[node0]     = ebeg + excl2;
    if (node0 + 1 < NNODES) off[node0 + 1] = ebeg + excl2 + a;
    __syncthreads();
    for (int e = ebeg + t; e < eend; e += 256) {
        int p = packed[e];
        int pos = ebeg + atomicAdd(&lcur[p & 511], 1);
        esrc[pos] = p >> 9;
    }
}

// ---- bf16 gather with 8/4-wide ILP: one cache line per edge row ----
__device__ __forceinline__ float gather_row_b(const ushort* __restrict__ x,
                                              const int* __restrict__ esrc,
                                              int beg, int end, int lane, float acc) {
    int i = beg;
    while (i + 8 <= end) {
        int s0 = esrc[i + 0], s1 = esrc[i + 1], s2 = esrc[i + 2], s3 = esrc[i + 3];
        int s4 = esrc[i + 4], s5 = esrc[i + 5], s6 = esrc[i + 6], s7 = esrc[i + 7];
        ushort v0 = x[(size_t)s0 * D + lane], v1 = x[(size_t)s1 * D + lane];
        ushort v2 = x[(size_t)s2 * D + lane], v3 = x[(size_t)s3 * D + lane];
        ushort v4 = x[(size_t)s4 * D + lane], v5 = x[(size_t)s5 * D + lane];
        ushort v6 = x[(size_t)s6 * D + lane], v7 = x[(size_t)s7 * D + lane];
        acc += ((b2f(v0) + b2f(v1)) + (b2f(v2) + b2f(v3))) +
               ((b2f(v4) + b2f(v5)) + (b2f(v6) + b2f(v7)));
        i += 8;
    }
    if (i + 4 <= end) {
        int s0 = esrc[i + 0], s1 = esrc[i + 1], s2 = esrc[i + 2], s3 = esrc[i + 3];
        ushort v0 = x[(size_t)s0 * D + lane], v1 = x[(size_t)s1 * D + lane];
        ushort v2 = x[(size_t)s2 * D + lane], v3 = x[(size_t)s3 * D + lane];
        acc += (b2f(v0) + b2f(v1)) + (b2f(v2) + b2f(v3));
        i += 4;
    }
    for (; i < end; ++i) acc += b2f(x[(size_t)esrc[i] * D + lane]);
    return acc;
}

// ---------------- pure gather (CSR): aggb[node] = x[node] + sum_src x[src] ----------------
__global__ void gather_kernel(const ushort* __restrict__ xb,
                              const int* __restrict__ off,
                              const int* __restrict__ esrc,
                              ushort* __restrict__ aggb, int n) {
    int tid = threadIdx.x;
    int w = tid >> 6, lane = tid & 63;
    int node = blockIdx.x * 4 + w;
    int stride = gridDim.x * 4;
    for (; node < n; node += stride) {
        float acc = b2f(xb[(size_t)node * D + lane]);
        acc = gather_row_b(xb, esrc, off[node], off[node + 1], lane, acc);
        aggb[(size_t)node * D + lane] = f2b(acc);
    }
}

// ---------------- MFMA GEMM: hb = bf16(relu(aggb @ W1 + b1)) ----------------
__global__ void gemm1_kernel(const ushort* __restrict__ aggb,
                             const ushort* __restrict__ Wswz,
                             const float* __restrict__ b1,
                             ushort* __restrict__ hb, int ntiles) {
    int tid = threadIdx.x;
    int w = tid >> 6, lane = tid & 63;
    int tile = blockIdx.x * 4 + w;
    if (tile >= ntiles) return;

    short8 bfrag[8];
#pragma unroll
    for (int j = 0; j < 8; ++j)
        bfrag[j] = *(const short8*)(Wswz + ((size_t)j * 64 + lane) * 8);

    int rbase = tile * 16;
    const ushort* arow = aggb + (size_t)(rbase + (lane & 15)) * D + (lane >> 4) * 8;
    short8 a0 = *(const short8*)(arow);
    short8 a1 = *(const short8*)(arow + 32);

    f32x4 acc0 = {0.f, 0.f, 0.f, 0.f};
    f32x4 acc1 = {0.f, 0.f, 0.f, 0.f};
    f32x4 acc2 = {0.f, 0.f, 0.f, 0.f};
    f32x4 acc3 = {0.f, 0.f, 0.f, 0.f};
    acc0 = __builtin_amdgcn_mfma_f32_16x16x32_bf16(a0, bfrag[0], acc0, 0, 0, 0);
    acc0 = __builtin_amdgcn_mfma_f32_16x16x32_bf16(a1, bfrag[1], acc0, 0, 0, 0);
    acc1 = __builtin_amdgcn_mfma_f32_16x16x32_bf16(a0, bfrag[2], acc1, 0, 0, 0);
    acc1 = __builtin_amdgcn_mfma_f32_16x16x32_bf16(a1, bfrag[3], acc1, 0, 0, 0);
    acc2 = __builtin_amdgcn_mfma_f32_16x16x32_bf16(a0, bfrag[4], acc2, 0, 0, 0);
    acc2 = __builtin_amdgcn_mfma_f32_16x16x32_bf16(a1, bfrag[5], acc2, 0, 0, 0);
    acc3 = __builtin_amdgcn_mfma_f32_16x16x32_bf16(a0, bfrag[6], acc3, 0, 0, 0);
    acc3 = __builtin_amdgcn_mfma_f32_16x16x32_bf16(a1, bfrag[7], acc3, 0, 0, 0);

    // C layout: col = 16c + (lane&15), row = (lane>>4)*4 + r
    int colb = lane & 15;
    int rowb = (lane >> 4) * 4;
#pragma unroll
    for (int r = 0; r < 4; ++r) {
        size_t rowoff = (size_t)(rbase + rowb + r) * D;
        hb[rowoff + colb +  0] = f2b(fmaxf(acc0[r] + b1[colb +  0], 0.f));
        hb[rowoff + colb + 16] = f2b(fmaxf(acc1[r] + b1[colb + 16], 0.f));
        hb[rowoff + colb + 32] = f2b(fmaxf(acc2[r] + b1[colb + 32], 0.f));
        hb[rowoff + colb + 48] = f2b(fmaxf(acc3[r] + b1[colb + 48], 0.f));
    }
}

// ------- gather2 (CSR) + pre-GEMM pooling: P[g] = sum_{node in g} (h[node]+agg2[node]) -------
__global__ void gather_pool_kernel(const ushort* __restrict__ hb,
                                   const int* __restrict__ off,
                                   const int* __restrict__ esrc,
                                   const int* __restrict__ gid,
                                   float* __restrict__ P,
                                   float* __restrict__ cntg, int n) {
    int tid = threadIdx.x;
    int w = tid >> 6, lane = tid & 63;
    int waves_total = gridDim.x * 4;
    int wave_id = blockIdx.x * 4 + w;
    int chunk = (n + waves_total - 1) / waves_total;
    int start = wave_id * chunk;
    int end = min(start + chunk, n);

    float accp = 0.f;
    int cur = -1, cc = 0;
    for (int node = start; node < end; ++node) {
        float acc = b2f(hb[(size_t)node * D + lane]);
        acc = gather_row_b(hb, esrc, off[node], off[node + 1], lane, acc);
        int g = gid[node];            // uniform across the wave (sorted)
        if (g != cur) {
            if (cur >= 0) {
                atomicAdd(&P[cur * D + lane], accp);
                if (lane == 0) atomicAdd(&cntg[cur], (float)cc);
            }
            cur = g; accp = 0.f; cc = 0;
        }
        accp += acc;
        cc++;
    }
    if (cur >= 0) {
        atomicAdd(&P[cur * D + lane], accp);
        if (lane == 0) atomicAdd(&cntg[cur], (float)cc);
    }
}

// ------- final tiny GEMM: out[g] = P[g] @ W2 + cntg[g] * b2 (f32) -------
__global__ void final_kernel(const float* __restrict__ P,
                             const float* __restrict__ cntg,
                             const float* __restrict__ W2,
                             const float* __restrict__ b2,
                             float* __restrict__ out) {
    __shared__ float Ws[D * D];
    __shared__ float bs[D];
    __shared__ float xs[4][D];
    int tid = threadIdx.x;
    for (int i = tid; i < D * D / 4; i += blockDim.x)
        ((float4*)Ws)[i] = ((const float4*)W2)[i];
    if (tid < D) bs[tid] = b2[tid];
    __syncthreads();

    int w = tid >> 6, lane = tid & 63;
    int g = blockIdx.x * 4 + w;
    if (g >= NGRAPHS) return;
    xs[w][lane] = P[g * D + lane];
    float acc = cntg[g] * bs[lane];
#pragma unroll
    for (int k = 0; k < D; ++k)
        acc = fmaf(xs[w][k], Ws[k * D + lane], acc);
    out[g * D + lane] = acc;
}

extern "C" void kernel_launch(void* const* d_in, const int* in_sizes, int n_in,
                              void* d_out, int out_size, void* d_ws, size_t ws_size,
                              hipStream_t stream) {
    const float* feats = (const float*)d_in[0];
    const int*   src   = (const int*)d_in[1];
    const int*   dst   = (const int*)d_in[2];
    const int*   gid   = (const int*)d_in[3];
    const float* W1    = (const float*)d_in[4];
    const float* b1    = (const float*)d_in[5];
    const float* W2    = (const float*)d_in[6];
    const float* b2    = (const float*)d_in[7];
    float* out = (float*)d_out;

    int nE = in_sizes[1];
    int nblk = (nE + EPB - 1) / EPB;       // binning blocks (~293)
    int M = NBUCK * nblk;
    int gb = (M + 1023) / 1024;            // scan blocks (~57)

    // workspace layout (all segments 16B-aligned)
    int*    bbase  = (int*)d_ws;                        // 256 ints (NBUCK+1 used)
    int*    gsum   = bbase + 256;                       // 256 ints
    int*    gbase2 = gsum + 256;                        // 256 ints
    float*  P      = (float*)(gbase2 + 256);            // 128*64 f32
    float*  cntg   = P + NGRAPHS * D;                   // 128 f32
    int*    off    = (int*)(cntg + 128);                // NNODES+4 ints
    int*    ghist  = off + ((NNODES + 7) & ~3);         // M ints (~230KB)
    int*    packed = ghist + ((M + 3) & ~3);            // nE ints
    int*    esrc   = packed + ((nE + 3) & ~3);          // nE ints
    ushort* Wswz   = (ushort*)(esrc + ((nE + 3) & ~3)); // 4096 bf16
    ushort* xb     = Wswz + 4096;                       // NNODES*D bf16
    ushort* aggb   = xb + (size_t)NNODES * D;           // NNODES*D bf16
    ushort* hb     = aggb + (size_t)NNODES * D;         // NNODES*D bf16

    // ---- CSR build via atomic-free 3-pass binning + per-bucket build ----
    bhist_kernel<<<nblk, 256, 0, stream>>>(dst, ghist, nE, nblk);
    gpartial_kernel<<<gb, 256, 0, stream>>>(ghist, gsum, M);
    gscanb_kernel<<<1, 256, 0, stream>>>(gsum, gbase2, bbase, off, gb, nE);
    goffsets_kernel<<<gb, 256, 0, stream>>>(ghist, gbase2, bbase, M, nblk);
    bscatter_kernel<<<nblk, 256, 0, stream>>>(src, dst, ghist, packed, nE, nblk);
    csr_build_kernel<<<NBUCK, 256, 0, stream>>>(packed, bbase, off, esrc);

    // ---- prep: cast feats to bf16, swizzle W1, zero P/cntg ----
    cast_kernel<<<2048, 256, 0, stream>>>(feats, xb, NNODES * D / 4);
    prep_w_kernel<<<1, 512, 0, stream>>>(W1, Wswz);
    zero_kernel<<<8, 256, 0, stream>>>((int*)P, (NGRAPHS * D + 128) / 4);

    // ---- layer 1: gather then MFMA GEMM ----
    gather_kernel<<<2048, 256, 0, stream>>>(xb, off, esrc, aggb, NNODES);
    gemm1_kernel<<<(NTILES + 3) / 4, 256, 0, stream>>>(aggb, Wswz, b1, hb, NTILES);

    // ---- layer 2: gather + pooled pre-GEMM sum, then tiny final GEMM ----
    gather_pool_kernel<<<2048, 256, 0, stream>>>(hb, off, esrc, gid, P, cntg, NNODES);
    final_kernel<<<NGRAPHS / 4, 256, 0, stream>>>(P, cntg, W2, b2, out);
}

// Round 11
// 165.091 us; speedup vs baseline: 5.1720x; 1.0522x over previous
//
#include <hip/hip_runtime.h>

#define D 64
#define NNODES 100000
#define NGRAPHS 128
#define NTILES ((NNODES + 15) / 16)   // 6250
#define BUCKW 512                     // nodes per bucket (power of 2)
#define NBUCK ((NNODES + BUCKW - 1) / BUCKW)   // 196
#define EPB 4096                      // edges per binning block (16/thread)

typedef unsigned int uint;
typedef unsigned short ushort;
typedef __attribute__((ext_vector_type(8))) short short8;   // 8 bf16 (4 VGPRs)
typedef __attribute__((ext_vector_type(4))) float f32x4;

// ---- bf16 helpers (RNE) ----
__device__ __forceinline__ ushort f2b(float f) {
    uint u = __float_as_uint(f);
    uint r = (u + 0x7fffu + ((u >> 16) & 1u)) >> 16;
    return (ushort)r;
}
__device__ __forceinline__ float b2f(ushort h) {
    return __uint_as_float(((uint)h) << 16);
}

// ---------------- zero buffer (int4 grid-stride) ----------------
__global__ void zero_kernel(int* __restrict__ buf, int n4) {
    int i = blockIdx.x * blockDim.x + threadIdx.x;
    int stride = gridDim.x * blockDim.x;
    int4 z = make_int4(0, 0, 0, 0);
    for (; i < n4; i += stride) ((int4*)buf)[i] = z;
}

// ---------------- f32 -> bf16 cast (float4 in, ushort4 out) ----------------
__global__ void cast_kernel(const float* __restrict__ in, ushort* __restrict__ outb, int n4) {
    int i = blockIdx.x * blockDim.x + threadIdx.x;
    int stride = gridDim.x * blockDim.x;
    for (; i < n4; i += stride) {
        float4 v = ((const float4*)in)[i];
        ushort4 o;
        o.x = f2b(v.x); o.y = f2b(v.y); o.z = f2b(v.z); o.w = f2b(v.w);
        ((ushort4*)outb)[i] = o;
    }
}

// -------- swizzle W1 (f32 [k][col] row-major) into MFMA B-fragment order --------
__global__ void prep_w_kernel(const float* __restrict__ W, ushort* __restrict__ Wswz) {
    int t = threadIdx.x;            // 0..511 = j*64 + lane
    int j = t >> 6, lane = t & 63;
    int c = j >> 1, h = j & 1;
    int col = 16 * c + (lane & 15);
    int kbase = (lane >> 4) * 8 + 32 * h;
#pragma unroll
    for (int i = 0; i < 8; ++i)
        Wswz[(size_t)t * 8 + i] = f2b(W[(kbase + i) * D + col]);
}

// ---- pass 1: per-block bucket histogram (LDS), written bucket-major, NO global atomics ----
__global__ void bhist_kernel(const int* __restrict__ dst, int* __restrict__ ghist,
                             int nE, int nblk) {
    __shared__ int lh[NBUCK];
    int t = threadIdx.x, blk = blockIdx.x;
    for (int i = t; i < NBUCK; i += 256) lh[i] = 0;
    __syncthreads();
    int base = blk * EPB + t * 16;
    if (base + 16 <= nE) {
#pragma unroll
        for (int j = 0; j < 4; ++j) {
            int4 d = *(const int4*)(dst + base + j * 4);
            atomicAdd(&lh[d.x >> 9], 1);
            atomicAdd(&lh[d.y >> 9], 1);
            atomicAdd(&lh[d.z >> 9], 1);
            atomicAdd(&lh[d.w >> 9], 1);
        }
    } else {
        int lim = min(base + 16, nE);
        for (int e = base; e < lim; ++e) atomicAdd(&lh[dst[e] >> 9], 1);
    }
    __syncthreads();
    for (int i = t; i < NBUCK; i += 256) ghist[(size_t)i * nblk + blk] = lh[i];
}

// ---- pass 2a: per-block coalesced reduction of ghist (1024 entries/block) ----
__global__ void gpartial_kernel(const int* __restrict__ g, int* __restrict__ gsum, int M) {
    __shared__ int sh[256];
    int t = threadIdx.x;
    int base = (blockIdx.x * 256 + t) * 4;
    int s = 0;
    if (base + 4 <= M) {
        int4 v = *(const int4*)(g + base);
        s = v.x + v.y + v.z + v.w;
    } else {
        for (int i = base; i < M; ++i) s += g[i];
    }
    sh[t] = s;
    __syncthreads();
    for (int d = 128; d > 0; d >>= 1) {
        if (t < d) sh[t] += sh[t + d];
        __syncthreads();
    }
    if (t == 0) gsum[blockIdx.x] = sh[0];
}

// ---- pass 2b: one small block scans the <=256 partial sums (exclusive) ----
__global__ void gscanb_kernel(const int* __restrict__ gsum, int* __restrict__ gbase2,
                              int* __restrict__ bbase, int* __restrict__ off,
                              int nb, int nE) {
    __shared__ int sh[256];
    int t = threadIdx.x;
    sh[t] = (t < nb) ? gsum[t] : 0;
    __syncthreads();
    for (int d = 1; d < 256; d <<= 1) {
        int u = (t >= d) ? sh[t - d] : 0;
        __syncthreads();
        sh[t] += u;
        __syncthreads();
    }
    if (t < nb) gbase2[t] = (t == 0) ? 0 : sh[t - 1];
    if (t == 0) {
        bbase[NBUCK] = nE;
        off[NNODES] = nE;
    }
}

// ---- pass 2c: per-block local scan + base -> exclusive bases in ghist; extract bbase ----
__global__ void goffsets_kernel(int* __restrict__ g, const int* __restrict__ gbase2,
                                int* __restrict__ bbase, int M, int nblk) {
    __shared__ int sh[256];
    int t = threadIdx.x;
    int base = (blockIdx.x * 256 + t) * 4;
    int v0 = 0, v1 = 0, v2 = 0, v3 = 0;
    if (base + 4 <= M) {
        int4 v = *(const int4*)(g + base);
        v0 = v.x; v1 = v.y; v2 = v.z; v3 = v.w;
    } else {
        if (base < M)     v0 = g[base];
        if (base + 1 < M) v1 = g[base + 1];
        if (base + 2 < M) v2 = g[base + 2];
        if (base + 3 < M) v3 = g[base + 3];
    }
    int s = v0 + v1 + v2 + v3;
    sh[t] = s;
    __syncthreads();
    for (int d = 1; d < 256; d <<= 1) {
        int u = (t >= d) ? sh[t - d] : 0;
        __syncthreads();
        sh[t] += u;
        __syncthreads();
    }
    int e0 = gbase2[blockIdx.x] + sh[t] - s;
    int e1 = e0 + v0, e2 = e1 + v1, e3 = e2 + v2;
    if (base + 4 <= M) {
        *(int4*)(g + base) = make_int4(e0, e1, e2, e3);
    } else {
        if (base < M)     g[base]     = e0;
        if (base + 1 < M) g[base + 1] = e1;
        if (base + 2 < M) g[base + 2] = e2;
        if (base + 3 < M) g[base + 3] = e3;
    }
    int ev[4] = {e0, e1, e2, e3};
#pragma unroll
    for (int j = 0; j < 4; ++j) {
        int i = base + j;
        if (i < M && i % nblk == 0) bbase[i / nblk] = ev[j];
    }
}

// ---- pass 3: scatter packed (src<<9 | dstlocal); LDS cursors, sequential stream writes ----
__global__ void bscatter_kernel(const int* __restrict__ src, const int* __restrict__ dst,
                                const int* __restrict__ gbase, int* __restrict__ packed,
                                int nE, int nblk) {
    __shared__ int lcur[NBUCK];
    int t = threadIdx.x, blk = blockIdx.x;
    for (int i = t; i < NBUCK; i += 256) lcur[i] = gbase[(size_t)i * nblk + blk];
    __syncthreads();
    int base = blk * EPB + t * 16;
    if (base + 16 <= nE) {
#pragma unroll
        for (int j = 0; j < 4; ++j) {
            int4 d = *(const int4*)(dst + base + j * 4);
            int4 s4 = *(const int4*)(src + base + j * 4);
            int p0 = atomicAdd(&lcur[d.x >> 9], 1);
            int p1 = atomicAdd(&lcur[d.y >> 9], 1);
            int p2 = atomicAdd(&lcur[d.z >> 9], 1);
            int p3 = atomicAdd(&lcur[d.w >> 9], 1);
            packed[p0] = (s4.x << 9) | (d.x & 511);
            packed[p1] = (s4.y << 9) | (d.y & 511);
            packed[p2] = (s4.z << 9) | (d.z & 511);
            packed[p3] = (s4.w << 9) | (d.w & 511);
        }
    } else {
        int lim = min(base + 16, nE);
        for (int e = base; e < lim; ++e) {
            int p = atomicAdd(&lcur[dst[e] >> 9], 1);
            packed[p] = (src[e] << 9) | (dst[e] & 511);
        }
    }
}

// ---------------- pass 4: per-bucket CSR build (one block per bucket) ----------------
__global__ void csr_build_kernel(const int* __restrict__ packed, const int* __restrict__ bbase,
                                 int* __restrict__ off, int* __restrict__ esrc) {
    __shared__ int lcnt[BUCKW];
    __shared__ int lcur[BUCKW];
    __shared__ int part[256];
    int t = threadIdx.x;
    int blk = blockIdx.x;
    int ebeg = bbase[blk], eend = bbase[blk + 1];
    lcnt[t] = 0; lcnt[t + 256] = 0;
    __syncthreads();
    for (int e = ebeg + t; e < eend; e += 256)
        atomicAdd(&lcnt[packed[e] & 511], 1);
    __syncthreads();
    int a = lcnt[2 * t], bv = lcnt[2 * t + 1];
    part[t] = a + bv;
    __syncthreads();
    for (int d = 1; d < 256; d <<= 1) {
        int u = (t >= d) ? part[t - d] : 0;
        __syncthreads();
        part[t] += u;
        __syncthreads();
    }
    int excl2 = (t == 0) ? 0 : part[t - 1];
    lcur[2 * t] = excl2;
    lcur[2 * t + 1] = excl2 + a;
    int node0 = blk * BUCKW + 2 * t;
    if (node0 < NNODES)     off[node0]     = ebeg + excl2;
    if (node0 + 1 < NNODES) off[node0 + 1] = ebeg + excl2 + a;
    __syncthreads();
    for (int e = ebeg + t; e < eend; e += 256) {
        int p = packed[e];
        int pos = ebeg + atomicAdd(&lcur[p & 511], 1);
        esrc[pos] = p >> 9;
    }
}

// ---- bf16 gather with 8/4-wide ILP (row-per-wave layout, used by gather_pool) ----
__device__ __forceinline__ float gather_row_b(const ushort* __restrict__ x,
                                              const int* __restrict__ esrc,
                                              int beg, int end, int lane, float acc) {
    int i = beg;
    while (i + 8 <= end) {
        int s0 = esrc[i + 0], s1 = esrc[i + 1], s2 = esrc[i + 2], s3 = esrc[i + 3];
        int s4 = esrc[i + 4], s5 = esrc[i + 5], s6 = esrc[i + 6], s7 = esrc[i + 7];
        ushort v0 = x[(size_t)s0 * D + lane], v1 = x[(size_t)s1 * D + lane];
        ushort v2 = x[(size_t)s2 * D + lane], v3 = x[(size_t)s3 * D + lane];
        ushort v4 = x[(size_t)s4 * D + lane], v5 = x[(size_t)s5 * D + lane];
        ushort v6 = x[(size_t)s6 * D + lane], v7 = x[(size_t)s7 * D + lane];
        acc += ((b2f(v0) + b2f(v1)) + (b2f(v2) + b2f(v3))) +
               ((b2f(v4) + b2f(v5)) + (b2f(v6) + b2f(v7)));
        i += 8;
    }
    if (i + 4 <= end) {
        int s0 = esrc[i + 0], s1 = esrc[i + 1], s2 = esrc[i + 2], s3 = esrc[i + 3];
        ushort v0 = x[(size_t)s0 * D + lane], v1 = x[(size_t)s1 * D + lane];
        ushort v2 = x[(size_t)s2 * D + lane], v3 = x[(size_t)s3 * D + lane];
        acc += (b2f(v0) + b2f(v1)) + (b2f(v2) + b2f(v3));
        i += 4;
    }
    for (; i < end; ++i) acc += b2f(x[(size_t)esrc[i] * D + lane]);
    return acc;
}

// ===== fused layer 1: gather into A-fragment registers + MFMA GEMM + relu =====
// Wave = 16-node tile. lane r=lane&15 (row), h=lane>>4 (k-chunk). Per edge of
// node r, the 4 lanes (r,h) read the full 128B x-row as 8x16B loads (same line
// count as the broadcast gather). Aggregation stays f32 in registers; aggb
// intermediate (25.6 MB round-trip) is eliminated.
__global__ void gather_gemm1_kernel(const ushort* __restrict__ xb,
                                    const int* __restrict__ off,
                                    const int* __restrict__ esrc,
                                    const ushort* __restrict__ Wswz,
                                    const float* __restrict__ b1,
                                    ushort* __restrict__ hb, int ntiles) {
    int tid = threadIdx.x;
    int w = tid >> 6, lane = tid & 63;
    int tile = blockIdx.x * 4 + w;
    if (tile >= ntiles) return;

    short8 bfrag[8];
#pragma unroll
    for (int j = 0; j < 8; ++j)
        bfrag[j] = *(const short8*)(Wswz + ((size_t)j * 64 + lane) * 8);

    int r = lane & 15, h = lane >> 4;
    int rbase = tile * 16;
    int node = rbase + r;

    float accA[8], accB[8];
    {
        const ushort* p = xb + (size_t)node * D + h * 8;
        short8 sA = *(const short8*)(p);
        short8 sB = *(const short8*)(p + 32);
#pragma unroll
        for (int q = 0; q < 8; ++q) {
            accA[q] = b2f((ushort)sA[q]);
            accB[q] = b2f((ushort)sB[q]);
        }
    }

    int beg = off[node], end = off[node + 1];
    int i = beg;
    for (; i + 4 <= end; i += 4) {
        int e0 = esrc[i], e1 = esrc[i + 1], e2 = esrc[i + 2], e3 = esrc[i + 3];
        const ushort* p0 = xb + (size_t)e0 * D + h * 8;
        const ushort* p1 = xb + (size_t)e1 * D + h * 8;
        const ushort* p2 = xb + (size_t)e2 * D + h * 8;
        const ushort* p3 = xb + (size_t)e3 * D + h * 8;
        short8 v0A = *(const short8*)(p0), v0B = *(const short8*)(p0 + 32);
        short8 v1A = *(const short8*)(p1), v1B = *(const short8*)(p1 + 32);
        short8 v2A = *(const short8*)(p2), v2B = *(const short8*)(p2 + 32);
        short8 v3A = *(const short8*)(p3), v3B = *(const short8*)(p3 + 32);
#pragma unroll
        for (int q = 0; q < 8; ++q) {
            accA[q] += (b2f((ushort)v0A[q]) + b2f((ushort)v1A[q]))
                     + (b2f((ushort)v2A[q]) + b2f((ushort)v3A[q]));
            accB[q] += (b2f((ushort)v0B[q]) + b2f((ushort)v1B[q]))
                     + (b2f((ushort)v2B[q]) + b2f((ushort)v3B[q]));
        }
    }
    for (; i < end; ++i) {
        const ushort* p = xb + (size_t)esrc[i] * D + h * 8;
        short8 vA = *(const short8*)(p), vB = *(const short8*)(p + 32);
#pragma unroll
        for (int q = 0; q < 8; ++q) {
            accA[q] += b2f((ushort)vA[q]);
            accB[q] += b2f((ushort)vB[q]);
        }
    }

    short8 a0, a1;
#pragma unroll
    for (int q = 0; q < 8; ++q) {
        a0[q] = (short)f2b(accA[q]);
        a1[q] = (short)f2b(accB[q]);
    }

    f32x4 acc0 = {0.f, 0.f, 0.f, 0.f};
    f32x4 acc1 = {0.f, 0.f, 0.f, 0.f};
    f32x4 acc2 = {0.f, 0.f, 0.f, 0.f};
    f32x4 acc3 = {0.f, 0.f, 0.f, 0.f};
    acc0 = __builtin_amdgcn_mfma_f32_16x16x32_bf16(a0, bfrag[0], acc0, 0, 0, 0);
    acc0 = __builtin_amdgcn_mfma_f32_16x16x32_bf16(a1, bfrag[1], acc0, 0, 0, 0);
    acc1 = __builtin_amdgcn_mfma_f32_16x16x32_bf16(a0, bfrag[2], acc1, 0, 0, 0);
    acc1 = __builtin_amdgcn_mfma_f32_16x16x32_bf16(a1, bfrag[3], acc1, 0, 0, 0);
    acc2 = __builtin_amdgcn_mfma_f32_16x16x32_bf16(a0, bfrag[4], acc2, 0, 0, 0);
    acc2 = __builtin_amdgcn_mfma_f32_16x16x32_bf16(a1, bfrag[5], acc2, 0, 0, 0);
    acc3 = __builtin_amdgcn_mfma_f32_16x16x32_bf16(a0, bfrag[6], acc3, 0, 0, 0);
    acc3 = __builtin_amdgcn_mfma_f32_16x16x32_bf16(a1, bfrag[7], acc3, 0, 0, 0);

    // C layout: col = 16c + (lane&15), row = (lane>>4)*4 + reg
    int colb = lane & 15;
    int rowb = (lane >> 4) * 4;
#pragma unroll
    for (int rr = 0; rr < 4; ++rr) {
        size_t rowoff = (size_t)(rbase + rowb + rr) * D;
        hb[rowoff + colb +  0] = f2b(fmaxf(acc0[rr] + b1[colb +  0], 0.f));
        hb[rowoff + colb + 16] = f2b(fmaxf(acc1[rr] + b1[colb + 16], 0.f));
        hb[rowoff + colb + 32] = f2b(fmaxf(acc2[rr] + b1[colb + 32], 0.f));
        hb[rowoff + colb + 48] = f2b(fmaxf(acc3[rr] + b1[colb + 48], 0.f));
    }
}

// ------- gather2 (CSR) + pre-GEMM pooling: P[g] = sum_{node in g} (h[node]+agg2[node]) -------
__global__ void gather_pool_kernel(const ushort* __restrict__ hb,
                                   const int* __restrict__ off,
                                   const int* __restrict__ esrc,
                                   const int* __restrict__ gid,
                                   float* __restrict__ P,
                                   float* __restrict__ cntg, int n) {
    int tid = threadIdx.x;
    int w = tid >> 6, lane = tid & 63;
    int waves_total = gridDim.x * 4;
    int wave_id = blockIdx.x * 4 + w;
    int chunk = (n + waves_total - 1) / waves_total;
    int start = wave_id * chunk;
    int end = min(start + chunk, n);

    float accp = 0.f;
    int cur = -1, cc = 0;
    for (int node = start; node < end; ++node) {
        float acc = b2f(hb[(size_t)node * D + lane]);
        acc = gather_row_b(hb, esrc, off[node], off[node + 1], lane, acc);
        int g = gid[node];            // uniform across the wave (sorted)
        if (g != cur) {
            if (cur >= 0) {
                atomicAdd(&P[cur * D + lane], accp);
                if (lane == 0) atomicAdd(&cntg[cur], (float)cc);
            }
            cur = g; accp = 0.f; cc = 0;
        }
        accp += acc;
        cc++;
    }
    if (cur >= 0) {
        atomicAdd(&P[cur * D + lane], accp);
        if (lane == 0) atomicAdd(&cntg[cur], (float)cc);
    }
}

// ------- final tiny GEMM: out[g] = P[g] @ W2 + cntg[g] * b2 (f32) -------
__global__ void final_kernel(const float* __restrict__ P,
                             const float* __restrict__ cntg,
                             const float* __restrict__ W2,
                             const float* __restrict__ b2,
                             float* __restrict__ out) {
    __shared__ float Ws[D * D];
    __shared__ float bs[D];
    __shared__ float xs[4][D];
    int tid = threadIdx.x;
    for (int i = tid; i < D * D / 4; i += blockDim.x)
        ((float4*)Ws)[i] = ((const float4*)W2)[i];
    if (tid < D) bs[tid] = b2[tid];
    __syncthreads();

    int w = tid >> 6, lane = tid & 63;
    int g = blockIdx.x * 4 + w;
    if (g >= NGRAPHS) return;
    xs[w][lane] = P[g * D + lane];
    float acc = cntg[g] * bs[lane];
#pragma unroll
    for (int k = 0; k < D; ++k)
        acc = fmaf(xs[w][k], Ws[k * D + lane], acc);
    out[g * D + lane] = acc;
}

extern "C" void kernel_launch(void* const* d_in, const int* in_sizes, int n_in,
                              void* d_out, int out_size, void* d_ws, size_t ws_size,
                              hipStream_t stream) {
    const float* feats = (const float*)d_in[0];
    const int*   src   = (const int*)d_in[1];
    const int*   dst   = (const int*)d_in[2];
    const int*   gid   = (const int*)d_in[3];
    const float* W1    = (const float*)d_in[4];
    const float* b1    = (const float*)d_in[5];
    const float* W2    = (const float*)d_in[6];
    const float* b2    = (const float*)d_in[7];
    float* out = (float*)d_out;

    int nE = in_sizes[1];
    int nblk = (nE + EPB - 1) / EPB;       // binning blocks (~293)
    int M = NBUCK * nblk;
    int gb = (M + 1023) / 1024;            // scan blocks (~57)

    // workspace layout (all segments 16B-aligned)
    int*    bbase  = (int*)d_ws;                        // 256 ints (NBUCK+1 used)
    int*    gsum   = bbase + 256;                       // 256 ints
    int*    gbase2 = gsum + 256;                        // 256 ints
    float*  P      = (float*)(gbase2 + 256);            // 128*64 f32
    float*  cntg   = P + NGRAPHS * D;                   // 128 f32
    int*    off    = (int*)(cntg + 128);                // NNODES+4 ints
    int*    ghist  = off + ((NNODES + 7) & ~3);         // M ints (~230KB)
    int*    packed = ghist + ((M + 3) & ~3);            // nE ints
    int*    esrc   = packed + ((nE + 3) & ~3);          // nE ints
    ushort* Wswz   = (ushort*)(esrc + ((nE + 3) & ~3)); // 4096 bf16
    ushort* xb     = Wswz + 4096;                       // NNODES*D bf16
    ushort* hb     = xb + (size_t)NNODES * D;           // NNODES*D bf16

    // ---- CSR build via atomic-free 3-pass binning + per-bucket build ----
    bhist_kernel<<<nblk, 256, 0, stream>>>(dst, ghist, nE, nblk);
    gpartial_kernel<<<gb, 256, 0, stream>>>(ghist, gsum, M);
    gscanb_kernel<<<1, 256, 0, stream>>>(gsum, gbase2, bbase, off, gb, nE);
    goffsets_kernel<<<gb, 256, 0, stream>>>(ghist, gbase2, bbase, M, nblk);
    bscatter_kernel<<<nblk, 256, 0, stream>>>(src, dst, ghist, packed, nE, nblk);
    csr_build_kernel<<<NBUCK, 256, 0, stream>>>(packed, bbase, off, esrc);

    // ---- prep: cast feats to bf16, swizzle W1, zero P/cntg ----
    cast_kernel<<<2048, 256, 0, stream>>>(feats, xb, NNODES * D / 4);
    prep_w_kernel<<<1, 512, 0, stream>>>(W1, Wswz);
    zero_kernel<<<8, 256, 0, stream>>>((int*)P, (NGRAPHS * D + 128) / 4);

    // ---- layer 1: fused gather + MFMA GEMM (no aggb intermediate) ----
    gather_gemm1_kernel<<<(NTILES + 3) / 4, 256, 0, stream>>>(xb, off, esrc, Wswz, b1, hb, NTILES);

    // ---- layer 2: gather + pooled pre-GEMM sum, then tiny final GEMM ----
    gather_pool_kernel<<<2048, 256, 0, stream>>>(hb, off, esrc, gid, P, cntg, NNODES);
    final_kernel<<<NGRAPHS / 4, 256, 0, stream>>>(P, cntg, W2, b2, out);
}

// Round 12
// 164.762 us; speedup vs baseline: 5.1824x; 1.0020x over previous
//
#include <hip/hip_runtime.h>

#define D 64
#define NNODES 100000
#define NGRAPHS 128
#define NTILES ((NNODES + 15) / 16)   // 6250
#define BUCKW 512                     // nodes per bucket (power of 2)
#define NBUCK ((NNODES + BUCKW - 1) / BUCKW)   // 196
#define EPB 4096                      // edges per binning block (16/thread)

typedef unsigned int uint;
typedef unsigned short ushort;
typedef __attribute__((ext_vector_type(8))) short short8;   // 8 bf16 (4 VGPRs)
typedef __attribute__((ext_vector_type(4))) float f32x4;

// ---- bf16 helpers (RNE) ----
__device__ __forceinline__ ushort f2b(float f) {
    uint u = __float_as_uint(f);
    uint r = (u + 0x7fffu + ((u >> 16) & 1u)) >> 16;
    return (ushort)r;
}
__device__ __forceinline__ float b2f(ushort h) {
    return __uint_as_float(((uint)h) << 16);
}

// ---------------- zero buffer (int4 grid-stride) ----------------
__global__ void zero_kernel(int* __restrict__ buf, int n4) {
    int i = blockIdx.x * blockDim.x + threadIdx.x;
    int stride = gridDim.x * blockDim.x;
    int4 z = make_int4(0, 0, 0, 0);
    for (; i < n4; i += stride) ((int4*)buf)[i] = z;
}

// ---------------- f32 -> bf16 cast (float4 in, ushort4 out) ----------------
__global__ void cast_kernel(const float* __restrict__ in, ushort* __restrict__ outb, int n4) {
    int i = blockIdx.x * blockDim.x + threadIdx.x;
    int stride = gridDim.x * blockDim.x;
    for (; i < n4; i += stride) {
        float4 v = ((const float4*)in)[i];
        ushort4 o;
        o.x = f2b(v.x); o.y = f2b(v.y); o.z = f2b(v.z); o.w = f2b(v.w);
        ((ushort4*)outb)[i] = o;
    }
}

// -------- swizzle W1 (f32 [k][col] row-major) into MFMA B-fragment order --------
__global__ void prep_w_kernel(const float* __restrict__ W, ushort* __restrict__ Wswz) {
    int t = threadIdx.x;            // 0..511 = j*64 + lane
    int j = t >> 6, lane = t & 63;
    int c = j >> 1, h = j & 1;
    int col = 16 * c + (lane & 15);
    int kbase = (lane >> 4) * 8 + 32 * h;
#pragma unroll
    for (int i = 0; i < 8; ++i)
        Wswz[(size_t)t * 8 + i] = f2b(W[(kbase + i) * D + col]);
}

// ---- pass 1: per-block bucket histogram (LDS), written bucket-major, NO global atomics ----
__global__ void bhist_kernel(const int* __restrict__ dst, int* __restrict__ ghist,
                             int nE, int nblk) {
    __shared__ int lh[NBUCK];
    int t = threadIdx.x, blk = blockIdx.x;
    for (int i = t; i < NBUCK; i += 256) lh[i] = 0;
    __syncthreads();
    int base = blk * EPB + t * 16;
    if (base + 16 <= nE) {
#pragma unroll
        for (int j = 0; j < 4; ++j) {
            int4 d = *(const int4*)(dst + base + j * 4);
            atomicAdd(&lh[d.x >> 9], 1);
            atomicAdd(&lh[d.y >> 9], 1);
            atomicAdd(&lh[d.z >> 9], 1);
            atomicAdd(&lh[d.w >> 9], 1);
        }
    } else {
        int lim = min(base + 16, nE);
        for (int e = base; e < lim; ++e) atomicAdd(&lh[dst[e] >> 9], 1);
    }
    __syncthreads();
    for (int i = t; i < NBUCK; i += 256) ghist[(size_t)i * nblk + blk] = lh[i];
}

// ---- pass 2a: per-block coalesced reduction of ghist (1024 entries/block) ----
__global__ void gpartial_kernel(const int* __restrict__ g, int* __restrict__ gsum, int M) {
    __shared__ int sh[256];
    int t = threadIdx.x;
    int base = (blockIdx.x * 256 + t) * 4;
    int s = 0;
    if (base + 4 <= M) {
        int4 v = *(const int4*)(g + base);
        s = v.x + v.y + v.z + v.w;
    } else {
        for (int i = base; i < M; ++i) s += g[i];
    }
    sh[t] = s;
    __syncthreads();
    for (int d = 128; d > 0; d >>= 1) {
        if (t < d) sh[t] += sh[t + d];
        __syncthreads();
    }
    if (t == 0) gsum[blockIdx.x] = sh[0];
}

// ---- pass 2b: one small block scans the <=256 partial sums (exclusive) ----
__global__ void gscanb_kernel(const int* __restrict__ gsum, int* __restrict__ gbase2,
                              int* __restrict__ bbase, int* __restrict__ off,
                              int nb, int nE) {
    __shared__ int sh[256];
    int t = threadIdx.x;
    sh[t] = (t < nb) ? gsum[t] : 0;
    __syncthreads();
    for (int d = 1; d < 256; d <<= 1) {
        int u = (t >= d) ? sh[t - d] : 0;
        __syncthreads();
        sh[t] += u;
        __syncthreads();
    }
    if (t < nb) gbase2[t] = (t == 0) ? 0 : sh[t - 1];
    if (t == 0) {
        bbase[NBUCK] = nE;
        off[NNODES] = nE;
    }
}

// ---- pass 2c: per-block local scan + base -> exclusive bases in ghist; extract bbase ----
__global__ void goffsets_kernel(int* __restrict__ g, const int* __restrict__ gbase2,
                                int* __restrict__ bbase, int M, int nblk) {
    __shared__ int sh[256];
    int t = threadIdx.x;
    int base = (blockIdx.x * 256 + t) * 4;
    int v0 = 0, v1 = 0, v2 = 0, v3 = 0;
    if (base + 4 <= M) {
        int4 v = *(const int4*)(g + base);
        v0 = v.x; v1 = v.y; v2 = v.z; v3 = v.w;
    } else {
        if (base < M)     v0 = g[base];
        if (base + 1 < M) v1 = g[base + 1];
        if (base + 2 < M) v2 = g[base + 2];
        if (base + 3 < M) v3 = g[base + 3];
    }
    int s = v0 + v1 + v2 + v3;
    sh[t] = s;
    __syncthreads();
    for (int d = 1; d < 256; d <<= 1) {
        int u = (t >= d) ? sh[t - d] : 0;
        __syncthreads();
        sh[t] += u;
        __syncthreads();
    }
    int e0 = gbase2[blockIdx.x] + sh[t] - s;
    int e1 = e0 + v0, e2 = e1 + v1, e3 = e2 + v2;
    if (base + 4 <= M) {
        *(int4*)(g + base) = make_int4(e0, e1, e2, e3);
    } else {
        if (base < M)     g[base]     = e0;
        if (base + 1 < M) g[base + 1] = e1;
        if (base + 2 < M) g[base + 2] = e2;
        if (base + 3 < M) g[base + 3] = e3;
    }
    int ev[4] = {e0, e1, e2, e3};
#pragma unroll
    for (int j = 0; j < 4; ++j) {
        int i = base + j;
        if (i < M && i % nblk == 0) bbase[i / nblk] = ev[j];
    }
}

// ---- pass 3: scatter packed (src<<9 | dstlocal); LDS cursors, sequential stream writes ----
__global__ void bscatter_kernel(const int* __restrict__ src, const int* __restrict__ dst,
                                const int* __restrict__ gbase, int* __restrict__ packed,
                                int nE, int nblk) {
    __shared__ int lcur[NBUCK];
    int t = threadIdx.x, blk = blockIdx.x;
    for (int i = t; i < NBUCK; i += 256) lcur[i] = gbase[(size_t)i * nblk + blk];
    __syncthreads();
    int base = blk * EPB + t * 16;
    if (base + 16 <= nE) {
#pragma unroll
        for (int j = 0; j < 4; ++j) {
            int4 d = *(const int4*)(dst + base + j * 4);
            int4 s4 = *(const int4*)(src + base + j * 4);
            int p0 = atomicAdd(&lcur[d.x >> 9], 1);
            int p1 = atomicAdd(&lcur[d.y >> 9], 1);
            int p2 = atomicAdd(&lcur[d.z >> 9], 1);
            int p3 = atomicAdd(&lcur[d.w >> 9], 1);
            packed[p0] = (s4.x << 9) | (d.x & 511);
            packed[p1] = (s4.y << 9) | (d.y & 511);
            packed[p2] = (s4.z << 9) | (d.z & 511);
            packed[p3] = (s4.w << 9) | (d.w & 511);
        }
    } else {
        int lim = min(base + 16, nE);
        for (int e = base; e < lim; ++e) {
            int p = atomicAdd(&lcur[dst[e] >> 9], 1);
            packed[p] = (src[e] << 9) | (dst[e] & 511);
        }
    }
}

// ---- pass 4: per-bucket CSR build + per-edge graph id (egid, sorted) ----
__global__ void csr_build_kernel(const int* __restrict__ packed, const int* __restrict__ bbase,
                                 const int* __restrict__ gid,
                                 int* __restrict__ off, int* __restrict__ esrc,
                                 int* __restrict__ egid) {
    __shared__ int lcnt[BUCKW];
    __shared__ int lcur[BUCKW];
    __shared__ int lgid[BUCKW];
    __shared__ int part[256];
    int t = threadIdx.x;
    int blk = blockIdx.x;
    int ebeg = bbase[blk], eend = bbase[blk + 1];
    lcnt[t] = 0; lcnt[t + 256] = 0;
    int n0 = blk * BUCKW + t, n1 = blk * BUCKW + t + 256;
    lgid[t]       = (n0 < NNODES) ? gid[n0] : 0;
    lgid[t + 256] = (n1 < NNODES) ? gid[n1] : 0;
    __syncthreads();
    for (int e = ebeg + t; e < eend; e += 256)
        atomicAdd(&lcnt[packed[e] & 511], 1);
    __syncthreads();
    int a = lcnt[2 * t], bv = lcnt[2 * t + 1];
    part[t] = a + bv;
    __syncthreads();
    for (int d = 1; d < 256; d <<= 1) {
        int u = (t >= d) ? part[t - d] : 0;
        __syncthreads();
        part[t] += u;
        __syncthreads();
    }
    int excl2 = (t == 0) ? 0 : part[t - 1];
    lcur[2 * t] = excl2;
    lcur[2 * t + 1] = excl2 + a;
    int node0 = blk * BUCKW + 2 * t;
    if (node0 < NNODES)     off[node0]     = ebeg + excl2;
    if (node0 + 1 < NNODES) off[node0 + 1] = ebeg + excl2 + a;
    __syncthreads();
    for (int e = ebeg + t; e < eend; e += 256) {
        int p = packed[e];
        int loc = p & 511;
        int pos = ebeg + atomicAdd(&lcur[loc], 1);
        esrc[pos] = p >> 9;
        egid[pos] = lgid[loc];
    }
}

// ===== fused layer 1: gather into A-fragment registers + MFMA GEMM + relu =====
__global__ void gather_gemm1_kernel(const ushort* __restrict__ xb,
                                    const int* __restrict__ off,
                                    const int* __restrict__ esrc,
                                    const ushort* __restrict__ Wswz,
                                    const float* __restrict__ b1,
                                    ushort* __restrict__ hb, int ntiles) {
    int tid = threadIdx.x;
    int w = tid >> 6, lane = tid & 63;
    int tile = blockIdx.x * 4 + w;
    if (tile >= ntiles) return;

    short8 bfrag[8];
#pragma unroll
    for (int j = 0; j < 8; ++j)
        bfrag[j] = *(const short8*)(Wswz + ((size_t)j * 64 + lane) * 8);

    int r = lane & 15, h = lane >> 4;
    int rbase = tile * 16;
    int node = rbase + r;

    float accA[8], accB[8];
    {
        const ushort* p = xb + (size_t)node * D + h * 8;
        short8 sA = *(const short8*)(p);
        short8 sB = *(const short8*)(p + 32);
#pragma unroll
        for (int q = 0; q < 8; ++q) {
            accA[q] = b2f((ushort)sA[q]);
            accB[q] = b2f((ushort)sB[q]);
        }
    }

    int beg = off[node], end = off[node + 1];
    int i = beg;
    for (; i + 4 <= end; i += 4) {
        int e0 = esrc[i], e1 = esrc[i + 1], e2 = esrc[i + 2], e3 = esrc[i + 3];
        const ushort* p0 = xb + (size_t)e0 * D + h * 8;
        const ushort* p1 = xb + (size_t)e1 * D + h * 8;
        const ushort* p2 = xb + (size_t)e2 * D + h * 8;
        const ushort* p3 = xb + (size_t)e3 * D + h * 8;
        short8 v0A = *(const short8*)(p0), v0B = *(const short8*)(p0 + 32);
        short8 v1A = *(const short8*)(p1), v1B = *(const short8*)(p1 + 32);
        short8 v2A = *(const short8*)(p2), v2B = *(const short8*)(p2 + 32);
        short8 v3A = *(const short8*)(p3), v3B = *(const short8*)(p3 + 32);
#pragma unroll
        for (int q = 0; q < 8; ++q) {
            accA[q] += (b2f((ushort)v0A[q]) + b2f((ushort)v1A[q]))
                     + (b2f((ushort)v2A[q]) + b2f((ushort)v3A[q]));
            accB[q] += (b2f((ushort)v0B[q]) + b2f((ushort)v1B[q]))
                     + (b2f((ushort)v2B[q]) + b2f((ushort)v3B[q]));
        }
    }
    for (; i < end; ++i) {
        const ushort* p = xb + (size_t)esrc[i] * D + h * 8;
        short8 vA = *(const short8*)(p), vB = *(const short8*)(p + 32);
#pragma unroll
        for (int q = 0; q < 8; ++q) {
            accA[q] += b2f((ushort)vA[q]);
            accB[q] += b2f((ushort)vB[q]);
        }
    }

    short8 a0, a1;
#pragma unroll
    for (int q = 0; q < 8; ++q) {
        a0[q] = (short)f2b(accA[q]);
        a1[q] = (short)f2b(accB[q]);
    }

    f32x4 acc0 = {0.f, 0.f, 0.f, 0.f};
    f32x4 acc1 = {0.f, 0.f, 0.f, 0.f};
    f32x4 acc2 = {0.f, 0.f, 0.f, 0.f};
    f32x4 acc3 = {0.f, 0.f, 0.f, 0.f};
    acc0 = __builtin_amdgcn_mfma_f32_16x16x32_bf16(a0, bfrag[0], acc0, 0, 0, 0);
    acc0 = __builtin_amdgcn_mfma_f32_16x16x32_bf16(a1, bfrag[1], acc0, 0, 0, 0);
    acc1 = __builtin_amdgcn_mfma_f32_16x16x32_bf16(a0, bfrag[2], acc1, 0, 0, 0);
    acc1 = __builtin_amdgcn_mfma_f32_16x16x32_bf16(a1, bfrag[3], acc1, 0, 0, 0);
    acc2 = __builtin_amdgcn_mfma_f32_16x16x32_bf16(a0, bfrag[4], acc2, 0, 0, 0);
    acc2 = __builtin_amdgcn_mfma_f32_16x16x32_bf16(a1, bfrag[5], acc2, 0, 0, 0);
    acc3 = __builtin_amdgcn_mfma_f32_16x16x32_bf16(a0, bfrag[6], acc3, 0, 0, 0);
    acc3 = __builtin_amdgcn_mfma_f32_16x16x32_bf16(a1, bfrag[7], acc3, 0, 0, 0);

    int colb = lane & 15;
    int rowb = (lane >> 4) * 4;
#pragma unroll
    for (int rr = 0; rr < 4; ++rr) {
        size_t rowoff = (size_t)(rbase + rowb + rr) * D;
        hb[rowoff + colb +  0] = f2b(fmaxf(acc0[rr] + b1[colb +  0], 0.f));
        hb[rowoff + colb + 16] = f2b(fmaxf(acc1[rr] + b1[colb + 16], 0.f));
        hb[rowoff + colb + 32] = f2b(fmaxf(acc2[rr] + b1[colb + 32], 0.f));
        hb[rowoff + colb + 48] = f2b(fmaxf(acc3[rr] + b1[colb + 48], 0.f));
    }
}

// ------- pool self-term: P[g] += sum_{node in g} h[node]; cntg[g] = |g| -------
__global__ void pool_self_kernel(const ushort* __restrict__ hb,
                                 const int* __restrict__ gid,
                                 float* __restrict__ P,
                                 float* __restrict__ cntg, int n) {
    int tid = threadIdx.x;
    int w = tid >> 6, lane = tid & 63;
    int waves_total = gridDim.x * 4;
    int wave_id = blockIdx.x * 4 + w;
    int chunk = (n + waves_total - 1) / waves_total;
    int start = wave_id * chunk;
    int end = min(start + chunk, n);

    float accp = 0.f;
    int cur = -1, cc = 0;
    for (int node = start; node < end; ++node) {
        float v = b2f(hb[(size_t)node * D + lane]);
        int g = gid[node];
        if (g != cur) {
            if (cur >= 0) {
                atomicAdd(&P[cur * D + lane], accp);
                if (lane == 0) atomicAdd(&cntg[cur], (float)cc);
            }
            cur = g; accp = 0.f; cc = 0;
        }
        accp += v;
        cc++;
    }
    if (cur >= 0) {
        atomicAdd(&P[cur * D + lane], accp);
        if (lane == 0) atomicAdd(&cntg[cur], (float)cc);
    }
}

// ------- edge-centric pooled gather: P[egid[e]] += h[esrc[e]] -------
// esrc/egid are CSR-ordered (egid sorted). Wave walks a contiguous 16-aligned
// edge range: vector int4 index/gid loads, 16 independent row loads in flight,
// register accumulate with boundary flush.
__global__ void edge_pool_kernel(const ushort* __restrict__ hb,
                                 const int* __restrict__ esrc,
                                 const int* __restrict__ egid,
                                 float* __restrict__ P, int nE) {
    int tid = threadIdx.x;
    int w = tid >> 6, lane = tid & 63;
    int waves_total = gridDim.x * 4;
    int wave_id = blockIdx.x * 4 + w;
    int chunk = ((nE + waves_total - 1) / waves_total + 15) & ~15;
    int start = wave_id * chunk;
    int end = min(start + chunk, nE);
    if (start >= nE) return;

    float accp = 0.f;
    int cur = -1;
    int i = start;
    for (; i + 16 <= end; i += 16) {
        int4 s0 = *(const int4*)(esrc + i);
        int4 s1 = *(const int4*)(esrc + i + 4);
        int4 s2 = *(const int4*)(esrc + i + 8);
        int4 s3 = *(const int4*)(esrc + i + 12);
        int4 g0 = *(const int4*)(egid + i);
        int4 g1 = *(const int4*)(egid + i + 4);
        int4 g2 = *(const int4*)(egid + i + 8);
        int4 g3 = *(const int4*)(egid + i + 12);
        ushort v0  = hb[(size_t)s0.x * D + lane];
        ushort v1  = hb[(size_t)s0.y * D + lane];
        ushort v2  = hb[(size_t)s0.z * D + lane];
        ushort v3  = hb[(size_t)s0.w * D + lane];
        ushort v4  = hb[(size_t)s1.x * D + lane];
        ushort v5  = hb[(size_t)s1.y * D + lane];
        ushort v6  = hb[(size_t)s1.z * D + lane];
        ushort v7  = hb[(size_t)s1.w * D + lane];
        ushort v8  = hb[(size_t)s2.x * D + lane];
        ushort v9  = hb[(size_t)s2.y * D + lane];
        ushort v10 = hb[(size_t)s2.z * D + lane];
        ushort v11 = hb[(size_t)s2.w * D + lane];
        ushort v12 = hb[(size_t)s3.x * D + lane];
        ushort v13 = hb[(size_t)s3.y * D + lane];
        ushort v14 = hb[(size_t)s3.z * D + lane];
        ushort v15 = hb[(size_t)s3.w * D + lane];
        int gg[16] = {g0.x, g0.y, g0.z, g0.w, g1.x, g1.y, g1.z, g1.w,
                      g2.x, g2.y, g2.z, g2.w, g3.x, g3.y, g3.z, g3.w};
        ushort vv[16] = {v0, v1, v2, v3, v4, v5, v6, v7,
                         v8, v9, v10, v11, v12, v13, v14, v15};
        // fast path: whole batch same graph (common: ~2100 boundaries / 75K batches)
        if (gg[0] == cur && gg[15] == cur) {
            float s = ((b2f(vv[0]) + b2f(vv[1])) + (b2f(vv[2]) + b2f(vv[3])))
                    + ((b2f(vv[4]) + b2f(vv[5])) + (b2f(vv[6]) + b2f(vv[7])))
                    + ((b2f(vv[8]) + b2f(vv[9])) + (b2f(vv[10]) + b2f(vv[11])))
                    + ((b2f(vv[12]) + b2f(vv[13])) + (b2f(vv[14]) + b2f(vv[15])));
            accp += s;
        } else {
#pragma unroll
            for (int q = 0; q < 16; ++q) {
                if (gg[q] != cur) {
                    if (cur >= 0) atomicAdd(&P[cur * D + lane], accp);
                    cur = gg[q]; accp = 0.f;
                }
                accp += b2f(vv[q]);
            }
        }
    }
    for (; i < end; ++i) {
        int g = egid[i];
        ushort v = hb[(size_t)esrc[i] * D + lane];
        if (g != cur) {
            if (cur >= 0) atomicAdd(&P[cur * D + lane], accp);
            cur = g; accp = 0.f;
        }
        accp += b2f(v);
    }
    if (cur >= 0) atomicAdd(&P[cur * D + lane], accp);
}

// ------- final tiny GEMM: out[g] = P[g] @ W2 + cntg[g] * b2 (f32) -------
__global__ void final_kernel(const float* __restrict__ P,
                             const float* __restrict__ cntg,
                             const float* __restrict__ W2,
                             const float* __restrict__ b2,
                             float* __restrict__ out) {
    __shared__ float Ws[D * D];
    __shared__ float bs[D];
    __shared__ float xs[4][D];
    int tid = threadIdx.x;
    for (int i = tid; i < D * D / 4; i += blockDim.x)
        ((float4*)Ws)[i] = ((const float4*)W2)[i];
    if (tid < D) bs[tid] = b2[tid];
    __syncthreads();

    int w = tid >> 6, lane = tid & 63;
    int g = blockIdx.x * 4 + w;
    if (g >= NGRAPHS) return;
    xs[w][lane] = P[g * D + lane];
    float acc = cntg[g] * bs[lane];
#pragma unroll
    for (int k = 0; k < D; ++k)
        acc = fmaf(xs[w][k], Ws[k * D + lane], acc);
    out[g * D + lane] = acc;
}

extern "C" void kernel_launch(void* const* d_in, const int* in_sizes, int n_in,
                              void* d_out, int out_size, void* d_ws, size_t ws_size,
                              hipStream_t stream) {
    const float* feats = (const float*)d_in[0];
    const int*   src   = (const int*)d_in[1];
    const int*   dst   = (const int*)d_in[2];
    const int*   gid   = (const int*)d_in[3];
    const float* W1    = (const float*)d_in[4];
    const float* b1    = (const float*)d_in[5];
    const float* W2    = (const float*)d_in[6];
    const float* b2    = (const float*)d_in[7];
    float* out = (float*)d_out;

    int nE = in_sizes[1];
    int nblk = (nE + EPB - 1) / EPB;       // binning blocks (~293)
    int M = NBUCK * nblk;
    int gb = (M + 1023) / 1024;            // scan blocks (~57)

    // workspace layout (all segments 16B-aligned)
    int*    bbase  = (int*)d_ws;                        // 256 ints (NBUCK+1 used)
    int*    gsum   = bbase + 256;                       // 256 ints
    int*    gbase2 = gsum + 256;                        // 256 ints
    float*  P      = (float*)(gbase2 + 256);            // 128*64 f32
    float*  cntg   = P + NGRAPHS * D;                   // 128 f32
    int*    off    = (int*)(cntg + 128);                // NNODES+4 ints
    int*    ghist  = off + ((NNODES + 7) & ~3);         // M ints (~230KB)
    int*    packed = ghist + ((M + 3) & ~3);            // nE ints
    int*    esrc   = packed + ((nE + 3) & ~3);          // nE ints
    int*    egid   = esrc + ((nE + 3) & ~3);            // nE ints
    ushort* Wswz   = (ushort*)(egid + ((nE + 3) & ~3)); // 4096 bf16
    ushort* xb     = Wswz + 4096;                       // NNODES*D bf16
    ushort* hb     = xb + (size_t)NNODES * D;           // NNODES*D bf16

    // ---- CSR build via atomic-free 3-pass binning + per-bucket build ----
    bhist_kernel<<<nblk, 256, 0, stream>>>(dst, ghist, nE, nblk);
    gpartial_kernel<<<gb, 256, 0, stream>>>(ghist, gsum, M);
    gscanb_kernel<<<1, 256, 0, stream>>>(gsum, gbase2, bbase, off, gb, nE);
    goffsets_kernel<<<gb, 256, 0, stream>>>(ghist, gbase2, bbase, M, nblk);
    bscatter_kernel<<<nblk, 256, 0, stream>>>(src, dst, ghist, packed, nE, nblk);
    csr_build_kernel<<<NBUCK, 256, 0, stream>>>(packed, bbase, gid, off, esrc, egid);

    // ---- prep: cast feats to bf16, swizzle W1, zero P/cntg ----
    cast_kernel<<<2048, 256, 0, stream>>>(feats, xb, NNODES * D / 4);
    prep_w_kernel<<<1, 512, 0, stream>>>(W1, Wswz);
    zero_kernel<<<8, 256, 0, stream>>>((int*)P, (NGRAPHS * D + 128) / 4);

    // ---- layer 1: fused gather + MFMA GEMM (no aggb intermediate) ----
    gather_gemm1_kernel<<<(NTILES + 3) / 4, 256, 0, stream>>>(xb, off, esrc, Wswz, b1, hb, NTILES);

    // ---- layer 2: self-term pool + edge-centric pooled gather, then tiny final GEMM ----
    pool_self_kernel<<<512, 256, 0, stream>>>(hb, gid, P, cntg, NNODES);
    edge_pool_kernel<<<2048, 256, 0, stream>>>(hb, esrc, egid, P, nE);
    final_kernel<<<NGRAPHS / 4, 256, 0, stream>>>(P, cntg, W2, b2, out);
}

// Round 13
// 138.209 us; speedup vs baseline: 6.1780x; 1.1921x over previous
//
#include <hip/hip_runtime.h>

#define D 64
#define NNODES 100000
#define NGRAPHS 128
#define NTILES ((NNODES + 15) / 16)   // 6250
#define BUCKW 512                     // nodes per bucket (power of 2)
#define NBUCK ((NNODES + BUCKW - 1) / BUCKW)   // 196
#define EPB 4096                      // edges per binning block (16/thread)
#define CASTB 1600                    // cast blocks inside prep_fused
#define SELFB 512                     // self-pool blocks inside pool_fused
#define EDGEB 2048                    // edge-pool blocks inside pool_fused

typedef unsigned int uint;
typedef unsigned short ushort;
typedef __attribute__((ext_vector_type(8))) short short8;   // 8 bf16 (4 VGPRs)
typedef __attribute__((ext_vector_type(4))) float f32x4;

// ---- bf16 helpers (RNE) ----
__device__ __forceinline__ ushort f2b(float f) {
    uint u = __float_as_uint(f);
    uint r = (u + 0x7fffu + ((u >> 16) & 1u)) >> 16;
    return (ushort)r;
}
__device__ __forceinline__ float b2f(ushort h) {
    return __uint_as_float(((uint)h) << 16);
}

// ===== fused prep: [0,nblk) bhist | [nblk,nblk+CASTB) cast | +1 prep_w | +1 zero P =====
__global__ void prep_fused_kernel(const float* __restrict__ feats, ushort* __restrict__ xb,
                                  const int* __restrict__ dst, int* __restrict__ ghist,
                                  const float* __restrict__ W1, ushort* __restrict__ Wswz,
                                  float* __restrict__ P, int nE, int nblk) {
    __shared__ int lh[NBUCK];
    int t = threadIdx.x, blk = blockIdx.x;
    if (blk < nblk) {
        // ---- bucket histogram (LDS, no global atomics) ----
        for (int i = t; i < NBUCK; i += 256) lh[i] = 0;
        __syncthreads();
        int base = blk * EPB + t * 16;
        if (base + 16 <= nE) {
#pragma unroll
            for (int j = 0; j < 4; ++j) {
                int4 d = *(const int4*)(dst + base + j * 4);
                atomicAdd(&lh[d.x >> 9], 1);
                atomicAdd(&lh[d.y >> 9], 1);
                atomicAdd(&lh[d.z >> 9], 1);
                atomicAdd(&lh[d.w >> 9], 1);
            }
        } else {
            int lim = min(base + 16, nE);
            for (int e = base; e < lim; ++e) atomicAdd(&lh[dst[e] >> 9], 1);
        }
        __syncthreads();
        for (int i = t; i < NBUCK; i += 256) ghist[(size_t)i * nblk + blk] = lh[i];
    } else if (blk < nblk + CASTB) {
        // ---- f32 -> bf16 cast ----
        int i = (blk - nblk) * 256 + t;
        int stride = CASTB * 256;
        int n4 = NNODES * D / 4;
        for (; i < n4; i += stride) {
            float4 v = ((const float4*)feats)[i];
            ushort4 o;
            o.x = f2b(v.x); o.y = f2b(v.y); o.z = f2b(v.z); o.w = f2b(v.w);
            ((ushort4*)xb)[i] = o;
        }
    } else if (blk == nblk + CASTB) {
        // ---- swizzle W1 into MFMA B-fragment order (512 logical threads) ----
        for (int half = 0; half < 2; ++half) {
            int tt = t + half * 256;
            int j = tt >> 6, lane = tt & 63;
            int c = j >> 1, h = j & 1;
            int col = 16 * c + (lane & 15);
            int kbase = (lane >> 4) * 8 + 32 * h;
#pragma unroll
            for (int i = 0; i < 8; ++i)
                Wswz[(size_t)tt * 8 + i] = f2b(W1[(kbase + i) * D + col]);
        }
    } else {
        // ---- zero P + cntg (NGRAPHS*D + 128 floats) ----
        int n4 = (NGRAPHS * D + 128) / 4;
        for (int i = t; i < n4; i += 256)
            ((int4*)P)[i] = make_int4(0, 0, 0, 0);
    }
}

// ---- pass 2a: per-block coalesced reduction of ghist (1024 entries/block) ----
__global__ void gpartial_kernel(const int* __restrict__ g, int* __restrict__ gsum, int M) {
    __shared__ int sh[256];
    int t = threadIdx.x;
    int base = (blockIdx.x * 256 + t) * 4;
    int s = 0;
    if (base + 4 <= M) {
        int4 v = *(const int4*)(g + base);
        s = v.x + v.y + v.z + v.w;
    } else {
        for (int i = base; i < M; ++i) s += g[i];
    }
    sh[t] = s;
    __syncthreads();
    for (int d = 128; d > 0; d >>= 1) {
        if (t < d) sh[t] += sh[t + d];
        __syncthreads();
    }
    if (t == 0) gsum[blockIdx.x] = sh[0];
}

// ---- pass 2b: one small block scans the <=256 partial sums (exclusive) ----
__global__ void gscanb_kernel(const int* __restrict__ gsum, int* __restrict__ gbase2,
                              int* __restrict__ bbase, int* __restrict__ off,
                              int nb, int nE) {
    __shared__ int sh[256];
    int t = threadIdx.x;
    sh[t] = (t < nb) ? gsum[t] : 0;
    __syncthreads();
    for (int d = 1; d < 256; d <<= 1) {
        int u = (t >= d) ? sh[t - d] : 0;
        __syncthreads();
        sh[t] += u;
        __syncthreads();
    }
    if (t < nb) gbase2[t] = (t == 0) ? 0 : sh[t - 1];
    if (t == 0) {
        bbase[NBUCK] = nE;
        off[NNODES] = nE;
    }
}

// ---- pass 2c: per-block local scan + base -> exclusive bases in ghist; extract bbase ----
__global__ void goffsets_kernel(int* __restrict__ g, const int* __restrict__ gbase2,
                                int* __restrict__ bbase, int M, int nblk) {
    __shared__ int sh[256];
    int t = threadIdx.x;
    int base = (blockIdx.x * 256 + t) * 4;
    int v0 = 0, v1 = 0, v2 = 0, v3 = 0;
    if (base + 4 <= M) {
        int4 v = *(const int4*)(g + base);
        v0 = v.x; v1 = v.y; v2 = v.z; v3 = v.w;
    } else {
        if (base < M)     v0 = g[base];
        if (base + 1 < M) v1 = g[base + 1];
        if (base + 2 < M) v2 = g[base + 2];
        if (base + 3 < M) v3 = g[base + 3];
    }
    int s = v0 + v1 + v2 + v3;
    sh[t] = s;
    __syncthreads();
    for (int d = 1; d < 256; d <<= 1) {
        int u = (t >= d) ? sh[t - d] : 0;
        __syncthreads();
        sh[t] += u;
        __syncthreads();
    }
    int e0 = gbase2[blockIdx.x] + sh[t] - s;
    int e1 = e0 + v0, e2 = e1 + v1, e3 = e2 + v2;
    if (base + 4 <= M) {
        *(int4*)(g + base) = make_int4(e0, e1, e2, e3);
    } else {
        if (base < M)     g[base]     = e0;
        if (base + 1 < M) g[base + 1] = e1;
        if (base + 2 < M) g[base + 2] = e2;
        if (base + 3 < M) g[base + 3] = e3;
    }
    int ev[4] = {e0, e1, e2, e3};
#pragma unroll
    for (int j = 0; j < 4; ++j) {
        int i = base + j;
        if (i < M && i % nblk == 0) bbase[i / nblk] = ev[j];
    }
}

// ---- pass 3: scatter packed (src<<9 | dstlocal); LDS cursors, sequential stream writes ----
__global__ void bscatter_kernel(const int* __restrict__ src, const int* __restrict__ dst,
                                const int* __restrict__ gbase, int* __restrict__ packed,
                                int nE, int nblk) {
    __shared__ int lcur[NBUCK];
    int t = threadIdx.x, blk = blockIdx.x;
    for (int i = t; i < NBUCK; i += 256) lcur[i] = gbase[(size_t)i * nblk + blk];
    __syncthreads();
    int base = blk * EPB + t * 16;
    if (base + 16 <= nE) {
#pragma unroll
        for (int j = 0; j < 4; ++j) {
            int4 d = *(const int4*)(dst + base + j * 4);
            int4 s4 = *(const int4*)(src + base + j * 4);
            int p0 = atomicAdd(&lcur[d.x >> 9], 1);
            int p1 = atomicAdd(&lcur[d.y >> 9], 1);
            int p2 = atomicAdd(&lcur[d.z >> 9], 1);
            int p3 = atomicAdd(&lcur[d.w >> 9], 1);
            packed[p0] = (s4.x << 9) | (d.x & 511);
            packed[p1] = (s4.y << 9) | (d.y & 511);
            packed[p2] = (s4.z << 9) | (d.z & 511);
            packed[p3] = (s4.w << 9) | (d.w & 511);
        }
    } else {
        int lim = min(base + 16, nE);
        for (int e = base; e < lim; ++e) {
            int p = atomicAdd(&lcur[dst[e] >> 9], 1);
            packed[p] = (src[e] << 9) | (dst[e] & 511);
        }
    }
}

// ---- pass 4: per-bucket CSR build + egid (512 threads, one node/thread) ----
__global__ void csr_build_kernel(const int* __restrict__ packed, const int* __restrict__ bbase,
                                 const int* __restrict__ gid,
                                 int* __restrict__ off, int* __restrict__ esrc,
                                 int* __restrict__ egid) {
    __shared__ int lcnt[BUCKW];
    __shared__ int lcur[BUCKW];
    __shared__ int lgid[BUCKW];
    __shared__ int part[BUCKW];
    int t = threadIdx.x;        // 0..511
    int blk = blockIdx.x;
    int ebeg = bbase[blk], eend = bbase[blk + 1];
    lcnt[t] = 0;
    int n0 = blk * BUCKW + t;
    lgid[t] = (n0 < NNODES) ? gid[n0] : 0;
    __syncthreads();
    for (int e = ebeg + t; e < eend; e += 512)
        atomicAdd(&lcnt[packed[e] & 511], 1);
    __syncthreads();
    int v = lcnt[t];
    part[t] = v;
    __syncthreads();
    for (int d = 1; d < 512; d <<= 1) {
        int u = (t >= d) ? part[t - d] : 0;
        __syncthreads();
        part[t] += u;
        __syncthreads();
    }
    int excl = part[t] - v;
    lcur[t] = excl;
    if (n0 < NNODES) off[n0] = ebeg + excl;
    __syncthreads();
    for (int e = ebeg + t; e < eend; e += 512) {
        int p = packed[e];
        int loc = p & 511;
        int pos = ebeg + atomicAdd(&lcur[loc], 1);
        esrc[pos] = p >> 9;
        egid[pos] = lgid[loc];
    }
}

// ===== fused layer 1: gather into A-fragment registers + MFMA GEMM + relu =====
__global__ void gather_gemm1_kernel(const ushort* __restrict__ xb,
                                    const int* __restrict__ off,
                                    const int* __restrict__ esrc,
                                    const ushort* __restrict__ Wswz,
                                    const float* __restrict__ b1,
                                    ushort* __restrict__ hb, int ntiles) {
    int tid = threadIdx.x;
    int w = tid >> 6, lane = tid & 63;
    int tile = blockIdx.x * 4 + w;
    if (tile >= ntiles) return;

    short8 bfrag[8];
#pragma unroll
    for (int j = 0; j < 8; ++j)
        bfrag[j] = *(const short8*)(Wswz + ((size_t)j * 64 + lane) * 8);

    int r = lane & 15, h = lane >> 4;
    int rbase = tile * 16;
    int node = rbase + r;

    float accA[8], accB[8];
    {
        const ushort* p = xb + (size_t)node * D + h * 8;
        short8 sA = *(const short8*)(p);
        short8 sB = *(const short8*)(p + 32);
#pragma unroll
        for (int q = 0; q < 8; ++q) {
            accA[q] = b2f((ushort)sA[q]);
            accB[q] = b2f((ushort)sB[q]);
        }
    }

    int beg = off[node], end = off[node + 1];
    int i = beg;
    for (; i + 4 <= end; i += 4) {
        int e0 = esrc[i], e1 = esrc[i + 1], e2 = esrc[i + 2], e3 = esrc[i + 3];
        const ushort* p0 = xb + (size_t)e0 * D + h * 8;
        const ushort* p1 = xb + (size_t)e1 * D + h * 8;
        const ushort* p2 = xb + (size_t)e2 * D + h * 8;
        const ushort* p3 = xb + (size_t)e3 * D + h * 8;
        short8 v0A = *(const short8*)(p0), v0B = *(const short8*)(p0 + 32);
        short8 v1A = *(const short8*)(p1), v1B = *(const short8*)(p1 + 32);
        short8 v2A = *(const short8*)(p2), v2B = *(const short8*)(p2 + 32);
        short8 v3A = *(const short8*)(p3), v3B = *(const short8*)(p3 + 32);
#pragma unroll
        for (int q = 0; q < 8; ++q) {
            accA[q] += (b2f((ushort)v0A[q]) + b2f((ushort)v1A[q]))
                     + (b2f((ushort)v2A[q]) + b2f((ushort)v3A[q]));
            accB[q] += (b2f((ushort)v0B[q]) + b2f((ushort)v1B[q]))
                     + (b2f((ushort)v2B[q]) + b2f((ushort)v3B[q]));
        }
    }
    for (; i < end; ++i) {
        const ushort* p = xb + (size_t)esrc[i] * D + h * 8;
        short8 vA = *(const short8*)(p), vB = *(const short8*)(p + 32);
#pragma unroll
        for (int q = 0; q < 8; ++q) {
            accA[q] += b2f((ushort)vA[q]);
            accB[q] += b2f((ushort)vB[q]);
        }
    }

    short8 a0, a1;
#pragma unroll
    for (int q = 0; q < 8; ++q) {
        a0[q] = (short)f2b(accA[q]);
        a1[q] = (short)f2b(accB[q]);
    }

    f32x4 acc0 = {0.f, 0.f, 0.f, 0.f};
    f32x4 acc1 = {0.f, 0.f, 0.f, 0.f};
    f32x4 acc2 = {0.f, 0.f, 0.f, 0.f};
    f32x4 acc3 = {0.f, 0.f, 0.f, 0.f};
    acc0 = __builtin_amdgcn_mfma_f32_16x16x32_bf16(a0, bfrag[0], acc0, 0, 0, 0);
    acc0 = __builtin_amdgcn_mfma_f32_16x16x32_bf16(a1, bfrag[1], acc0, 0, 0, 0);
    acc1 = __builtin_amdgcn_mfma_f32_16x16x32_bf16(a0, bfrag[2], acc1, 0, 0, 0);
    acc1 = __builtin_amdgcn_mfma_f32_16x16x32_bf16(a1, bfrag[3], acc1, 0, 0, 0);
    acc2 = __builtin_amdgcn_mfma_f32_16x16x32_bf16(a0, bfrag[4], acc2, 0, 0, 0);
    acc2 = __builtin_amdgcn_mfma_f32_16x16x32_bf16(a1, bfrag[5], acc2, 0, 0, 0);
    acc3 = __builtin_amdgcn_mfma_f32_16x16x32_bf16(a0, bfrag[6], acc3, 0, 0, 0);
    acc3 = __builtin_amdgcn_mfma_f32_16x16x32_bf16(a1, bfrag[7], acc3, 0, 0, 0);

    int colb = lane & 15;
    int rowb = (lane >> 4) * 4;
#pragma unroll
    for (int rr = 0; rr < 4; ++rr) {
        size_t rowoff = (size_t)(rbase + rowb + rr) * D;
        hb[rowoff + colb +  0] = f2b(fmaxf(acc0[rr] + b1[colb +  0], 0.f));
        hb[rowoff + colb + 16] = f2b(fmaxf(acc1[rr] + b1[colb + 16], 0.f));
        hb[rowoff + colb + 32] = f2b(fmaxf(acc2[rr] + b1[colb + 32], 0.f));
        hb[rowoff + colb + 48] = f2b(fmaxf(acc3[rr] + b1[colb + 48], 0.f));
    }
}

// ===== fused pooling: [0,SELFB) self-term+cnt | [SELFB,SELFB+EDGEB) edge-centric =====
__global__ void pool_fused_kernel(const ushort* __restrict__ hb,
                                  const int* __restrict__ gid,
                                  const int* __restrict__ esrc,
                                  const int* __restrict__ egid,
                                  float* __restrict__ P,
                                  float* __restrict__ cntg, int n, int nE) {
    int tid = threadIdx.x;
    int w = tid >> 6, lane = tid & 63;
    int blk = blockIdx.x;

    if (blk < SELFB) {
        // ---- self-term: P[g] += sum h[node]; cntg[g] = |g| ----
        int waves_total = SELFB * 4;
        int wave_id = blk * 4 + w;
        int chunk = (n + waves_total - 1) / waves_total;
        int start = wave_id * chunk;
        int end = min(start + chunk, n);
        float accp = 0.f;
        int cur = -1, cc = 0;
        for (int node = start; node < end; ++node) {
            float v = b2f(hb[(size_t)node * D + lane]);
            int g = gid[node];
            if (g != cur) {
                if (cur >= 0) {
                    atomicAdd(&P[cur * D + lane], accp);
                    if (lane == 0) atomicAdd(&cntg[cur], (float)cc);
                }
                cur = g; accp = 0.f; cc = 0;
            }
            accp += v;
            cc++;
        }
        if (cur >= 0) {
            atomicAdd(&P[cur * D + lane], accp);
            if (lane == 0) atomicAdd(&cntg[cur], (float)cc);
        }
        return;
    }

    // ---- edge-centric pooled gather: P[egid[e]] += h[esrc[e]] ----
    int waves_total = EDGEB * 4;
    int wave_id = (blk - SELFB) * 4 + w;
    int chunk = ((nE + waves_total - 1) / waves_total + 15) & ~15;
    int start = wave_id * chunk;
    int end = min(start + chunk, nE);
    if (start >= nE) return;

    float accp = 0.f;
    int cur = -1;
    int i = start;
    for (; i + 16 <= end; i += 16) {
        int4 s0 = *(const int4*)(esrc + i);
        int4 s1 = *(const int4*)(esrc + i + 4);
        int4 s2 = *(const int4*)(esrc + i + 8);
        int4 s3 = *(const int4*)(esrc + i + 12);
        int4 g0 = *(const int4*)(egid + i);
        int4 g1 = *(const int4*)(egid + i + 4);
        int4 g2 = *(const int4*)(egid + i + 8);
        int4 g3 = *(const int4*)(egid + i + 12);
        ushort v0  = hb[(size_t)s0.x * D + lane];
        ushort v1  = hb[(size_t)s0.y * D + lane];
        ushort v2  = hb[(size_t)s0.z * D + lane];
        ushort v3  = hb[(size_t)s0.w * D + lane];
        ushort v4  = hb[(size_t)s1.x * D + lane];
        ushort v5  = hb[(size_t)s1.y * D + lane];
        ushort v6  = hb[(size_t)s1.z * D + lane];
        ushort v7  = hb[(size_t)s1.w * D + lane];
        ushort v8  = hb[(size_t)s2.x * D + lane];
        ushort v9  = hb[(size_t)s2.y * D + lane];
        ushort v10 = hb[(size_t)s2.z * D + lane];
        ushort v11 = hb[(size_t)s2.w * D + lane];
        ushort v12 = hb[(size_t)s3.x * D + lane];
        ushort v13 = hb[(size_t)s3.y * D + lane];
        ushort v14 = hb[(size_t)s3.z * D + lane];
        ushort v15 = hb[(size_t)s3.w * D + lane];
        int gg[16] = {g0.x, g0.y, g0.z, g0.w, g1.x, g1.y, g1.z, g1.w,
                      g2.x, g2.y, g2.z, g2.w, g3.x, g3.y, g3.z, g3.w};
        ushort vv[16] = {v0, v1, v2, v3, v4, v5, v6, v7,
                         v8, v9, v10, v11, v12, v13, v14, v15};
        if (gg[0] == cur && gg[15] == cur) {
            float s = ((b2f(vv[0]) + b2f(vv[1])) + (b2f(vv[2]) + b2f(vv[3])))
                    + ((b2f(vv[4]) + b2f(vv[5])) + (b2f(vv[6]) + b2f(vv[7])))
                    + ((b2f(vv[8]) + b2f(vv[9])) + (b2f(vv[10]) + b2f(vv[11])))
                    + ((b2f(vv[12]) + b2f(vv[13])) + (b2f(vv[14]) + b2f(vv[15])));
            accp += s;
        } else {
#pragma unroll
            for (int q = 0; q < 16; ++q) {
                if (gg[q] != cur) {
                    if (cur >= 0) atomicAdd(&P[cur * D + lane], accp);
                    cur = gg[q]; accp = 0.f;
                }
                accp += b2f(vv[q]);
            }
        }
    }
    for (; i < end; ++i) {
        int g = egid[i];
        ushort v = hb[(size_t)esrc[i] * D + lane];
        if (g != cur) {
            if (cur >= 0) atomicAdd(&P[cur * D + lane], accp);
            cur = g; accp = 0.f;
        }
        accp += b2f(v);
    }
    if (cur >= 0) atomicAdd(&P[cur * D + lane], accp);
}

// ------- final tiny GEMM: out[g] = P[g] @ W2 + cntg[g] * b2 (f32) -------
__global__ void final_kernel(const float* __restrict__ P,
                             const float* __restrict__ cntg,
                             const float* __restrict__ W2,
                             const float* __restrict__ b2,
                             float* __restrict__ out) {
    __shared__ float Ws[D * D];
    __shared__ float bs[D];
    __shared__ float xs[4][D];
    int tid = threadIdx.x;
    for (int i = tid; i < D * D / 4; i += blockDim.x)
        ((float4*)Ws)[i] = ((const float4*)W2)[i];
    if (tid < D) bs[tid] = b2[tid];
    __syncthreads();

    int w = tid >> 6, lane = tid & 63;
    int g = blockIdx.x * 4 + w;
    if (g >= NGRAPHS) return;
    xs[w][lane] = P[g * D + lane];
    float acc = cntg[g] * bs[lane];
#pragma unroll
    for (int k = 0; k < D; ++k)
        acc = fmaf(xs[w][k], Ws[k * D + lane], acc);
    out[g * D + lane] = acc;
}

extern "C" void kernel_launch(void* const* d_in, const int* in_sizes, int n_in,
                              void* d_out, int out_size, void* d_ws, size_t ws_size,
                              hipStream_t stream) {
    const float* feats = (const float*)d_in[0];
    const int*   src   = (const int*)d_in[1];
    const int*   dst   = (const int*)d_in[2];
    const int*   gid   = (const int*)d_in[3];
    const float* W1    = (const float*)d_in[4];
    const float* b1    = (const float*)d_in[5];
    const float* W2    = (const float*)d_in[6];
    const float* b2    = (const float*)d_in[7];
    float* out = (float*)d_out;

    int nE = in_sizes[1];
    int nblk = (nE + EPB - 1) / EPB;       // binning blocks (~293)
    int M = NBUCK * nblk;
    int gb = (M + 1023) / 1024;            // scan blocks (~57)

    // workspace layout (all segments 16B-aligned)
    int*    bbase  = (int*)d_ws;                        // 256 ints (NBUCK+1 used)
    int*    gsum   = bbase + 256;                       // 256 ints
    int*    gbase2 = gsum + 256;                        // 256 ints
    float*  P      = (float*)(gbase2 + 256);            // 128*64 f32
    float*  cntg   = P + NGRAPHS * D;                   // 128 f32
    int*    off    = (int*)(cntg + 128);                // NNODES+4 ints
    int*    ghist  = off + ((NNODES + 7) & ~3);         // M ints (~230KB)
    int*    packed = ghist + ((M + 3) & ~3);            // nE ints
    int*    esrc   = packed + ((nE + 3) & ~3);          // nE ints
    int*    egid   = esrc + ((nE + 3) & ~3);            // nE ints
    ushort* Wswz   = (ushort*)(egid + ((nE + 3) & ~3)); // 4096 bf16
    ushort* xb     = Wswz + 4096;                       // NNODES*D bf16
    ushort* hb     = xb + (size_t)NNODES * D;           // NNODES*D bf16

    // ---- fused prep: bhist | cast | prep_w | zero P ----
    prep_fused_kernel<<<nblk + CASTB + 2, 256, 0, stream>>>(
        feats, xb, dst, ghist, W1, Wswz, P, nE, nblk);

    // ---- exact per-(bucket,block) bases via 3-phase scan ----
    gpartial_kernel<<<gb, 256, 0, stream>>>(ghist, gsum, M);
    gscanb_kernel<<<1, 256, 0, stream>>>(gsum, gbase2, bbase, off, gb, nE);
    goffsets_kernel<<<gb, 256, 0, stream>>>(ghist, gbase2, bbase, M, nblk);

    // ---- scatter to bucket streams, then per-bucket CSR build ----
    bscatter_kernel<<<nblk, 256, 0, stream>>>(src, dst, ghist, packed, nE, nblk);
    csr_build_kernel<<<NBUCK, 512, 0, stream>>>(packed, bbase, gid, off, esrc, egid);

    // ---- layer 1: fused gather + MFMA GEMM ----
    gather_gemm1_kernel<<<(NTILES + 3) / 4, 256, 0, stream>>>(xb, off, esrc, Wswz, b1, hb, NTILES);

    // ---- layer 2: fused self-pool + edge-centric pooled gather ----
    pool_fused_kernel<<<SELFB + EDGEB, 256, 0, stream>>>(hb, gid, esrc, egid, P, cntg, NNODES, nE);

    // ---- final tiny GEMM ----
    final_kernel<<<NGRAPHS / 4, 256, 0, stream>>>(P, cntg, W2, b2, out);
}